// Round 2
// baseline (1663.552 us; speedup 1.0000x reference)
//
#include <hip/hip_runtime.h>

typedef unsigned short u16;
typedef __bf16 bf16x8 __attribute__((ext_vector_type(8)));
typedef float f32x4 __attribute__((ext_vector_type(4)));
typedef u16 u16x8 __attribute__((ext_vector_type(8)));

#define B_ 16
#define F_ 2048
#define HOP_ 512
#define CL_ 32
#define W_ 16
#define STEPS_ 48

typedef const __attribute__((address_space(1))) void* gas_t;
typedef __attribute__((address_space(3))) void* las_t;

__device__ __forceinline__ void gload16(const void* g, void* l){
  __builtin_amdgcn_global_load_lds((gas_t)g, (las_t)l, 16, 0, 0);
}

__device__ __forceinline__ u16 f2bf(float f){
  unsigned u = __float_as_uint(f);
  return (u16)((u + 0x7FFFu + ((u >> 16) & 1u)) >> 16);
}

__device__ __forceinline__ f32x4 mfma16(bf16x8 a, bf16x8 b, f32x4 c){
  return __builtin_amdgcn_mfma_f32_16x16x32_bf16(a, b, c, 0, 0, 0);
}

// ---------- PB = proj @ Min, PD = proj @ Mdir  (32x1024 each) ----------
__global__ __launch_bounds__(128) void pb_kernel(
    const float* __restrict__ proj, const float* __restrict__ Min,
    const float* __restrict__ Mdir, float* __restrict__ PB, float* __restrict__ PD)
{
  int c = blockIdx.y;
  const float* M = blockIdx.z ? Mdir : Min;
  float* P = blockIdx.z ? PD : PB;
  int i = blockIdx.x * 128 + threadIdx.x;
  float acc = 0.f;
  #pragma unroll 4
  for (int k = 0; k < 1024; ++k) acc += proj[c*1024 + k] * M[k*1024 + i];
  P[c*1024 + i] = acc;
}

// ---------- transpose + cast to bf16: dst[i][k] = (bf16)src[k][i] ----------
__global__ __launch_bounds__(256) void tcast_kernel(
    const float* __restrict__ A, const float* __restrict__ C,
    u16* __restrict__ At, u16* __restrict__ Ct)
{
  __shared__ float tile[64][65];
  const float* src = blockIdx.z ? C : A;
  u16* dst = blockIdx.z ? Ct : At;
  int k0 = blockIdx.y * 64, i0 = blockIdx.x * 64;
  int t = threadIdx.x;
  int r = t >> 2, cq = (t & 3) * 16;
  #pragma unroll
  for (int q = 0; q < 4; ++q){
    float4 v = *(const float4*)(src + (long)(k0 + r)*1024 + i0 + cq + q*4);
    tile[r][cq + q*4 + 0] = v.x; tile[r][cq + q*4 + 1] = v.y;
    tile[r][cq + q*4 + 2] = v.z; tile[r][cq + q*4 + 3] = v.w;
  }
  __syncthreads();
  u16x8 o0, o1;
  #pragma unroll
  for (int j = 0; j < 8; ++j) o0[j] = f2bf(tile[cq + j][r]);
  #pragma unroll
  for (int j = 0; j < 8; ++j) o1[j] = f2bf(tile[cq + 8 + j][r]);
  *(u16x8*)(dst + (long)(i0 + r)*1024 + k0 + cq)     = o0;
  *(u16x8*)(dst + (long)(i0 + r)*1024 + k0 + cq + 8) = o1;
}

// ---------- U[b][f][i] = sum_c ctrl[b][c][f] * PB[c][i]  (f32) ----------
__global__ __launch_bounds__(256) void uprep_kernel(
    const float* __restrict__ ctrl, const float* __restrict__ PB, float* __restrict__ U)
{
  __shared__ float cl[8][32];
  int b = blockIdx.y, f0 = blockIdx.x * 8;
  int t = threadIdx.x;
  { int c = t >> 3, lf = t & 7; cl[lf][c] = ctrl[((long)b*32 + c)*F_ + f0 + lf]; }
  __syncthreads();
  int lf = t >> 5, kb = (t & 31) * 32;
  float acc[32];
  #pragma unroll
  for (int q = 0; q < 32; ++q) acc[q] = 0.f;
  for (int c = 0; c < 32; ++c){
    float s = cl[lf][c];
    const float4* p = (const float4*)(PB + c*1024 + kb);
    #pragma unroll
    for (int q = 0; q < 8; ++q){
      float4 v = p[q];
      acc[q*4+0] += s*v.x; acc[q*4+1] += s*v.y;
      acc[q*4+2] += s*v.z; acc[q*4+3] += s*v.w;
    }
  }
  float4* o = (float4*)(U + ((long)b*F_ + f0 + lf)*1024 + kb);
  #pragma unroll
  for (int q = 0; q < 8; ++q) o[q] = make_float4(acc[q*4+0], acc[q*4+1], acc[q*4+2], acc[q*4+3]);
}

// ---------- one scan step: S_new = S_prev @ A + U   (bf16 MFMA, rows = b*64+c) ----------
__global__ __launch_bounds__(256) void scan_step_kernel(
    const u16* __restrict__ src, int srcMode, int srcF0,
    u16* __restrict__ dst, int dstMode,
    const float* __restrict__ U, int uF0,
    const u16* __restrict__ Bt, int hasPrev)
{
  __shared__ u16 As[64*64];
  __shared__ u16 Bs[64*64];
  int t = threadIdx.x, lane = t & 63, wave = t >> 6;
  int n0 = blockIdx.x * 64, b = blockIdx.y;
  int wr = wave >> 1, wc = wave & 1;
  f32x4 acc[2][2];
  #pragma unroll
  for (int m = 0; m < 2; ++m)
    #pragma unroll
    for (int n = 0; n < 2; ++n)
      #pragma unroll
      for (int i = 0; i < 4; ++i){
        int c = wr*32 + m*16 + ((lane >> 4) << 2) + i;
        int f = c*CL_ + uF0;
        int col = n0 + wc*32 + n*16 + (lane & 15);
        acc[m][n][i] = (f >= 0) ? U[((long)b*F_ + f)*1024 + col] : 0.f;
      }
  if (hasPrev){
    for (int kt = 0; kt < 1024; kt += 64){
      #pragma unroll
      for (int s = 0; s < 2; ++s){
        int seg = wave*2 + s;
        int rc = seg*8 + (lane >> 3);
        int ck = lane & 7;
        long aoff;
        if (srcMode == 0) aoff = ((long)b*64 + rc) * 1024;
        else              aoff = ((long)b*F_ + rc*CL_ + srcF0) * 1024;
        gload16(src + aoff + kt + ck*8, (char*)As + seg*1024);
        gload16(Bt + ((long)n0 + rc)*1024 + kt + ck*8, (char*)Bs + seg*1024);
      }
      __syncthreads();
      #pragma unroll
      for (int kk = 0; kk < 2; ++kk){
        bf16x8 aF[2], bF[2];
        #pragma unroll
        for (int m = 0; m < 2; ++m)
          aF[m] = *(const bf16x8*)(As + (wr*32 + m*16 + (lane & 15))*64 + kk*32 + ((lane >> 4) << 3));
        #pragma unroll
        for (int n = 0; n < 2; ++n)
          bF[n] = *(const bf16x8*)(Bs + (wc*32 + n*16 + (lane & 15))*64 + kk*32 + ((lane >> 4) << 3));
        #pragma unroll
        for (int m = 0; m < 2; ++m)
          #pragma unroll
          for (int n = 0; n < 2; ++n)
            acc[m][n] = mfma16(aF[m], bF[n], acc[m][n]);
      }
      __syncthreads();
    }
  }
  #pragma unroll
  for (int m = 0; m < 2; ++m)
    #pragma unroll
    for (int n = 0; n < 2; ++n)
      #pragma unroll
      for (int i = 0; i < 4; ++i){
        int c = wr*32 + m*16 + ((lane >> 4) << 2) + i;
        int col = n0 + wc*32 + n*16 + (lane & 15);
        long doff = (dstMode == 0) ? ((long)b*64 + c)*1024
                                   : ((long)b*F_ + c*CL_ + uF0)*1024;
        dst[doff + col] = f2bf(acc[m][n][i]);
      }
}

// ---------- Y = S @ C  (M=32768, f32 out into U buffer) ----------
__global__ __launch_bounds__(256) void ygemm_kernel(
    const u16* __restrict__ S, const u16* __restrict__ Ct, float* __restrict__ Y)
{
  __shared__ u16 As[128*64];
  __shared__ u16 Bs[128*64];
  int t = threadIdx.x, lane = t & 63, wave = t >> 6;
  long r0 = (long)blockIdx.y * 128;
  int n0 = blockIdx.x * 128;
  int wr = wave >> 1, wc = wave & 1;
  f32x4 acc[4][4];
  #pragma unroll
  for (int m = 0; m < 4; ++m)
    #pragma unroll
    for (int n = 0; n < 4; ++n)
      acc[m][n] = (f32x4){0.f,0.f,0.f,0.f};
  for (int kt = 0; kt < 1024; kt += 64){
    #pragma unroll
    for (int s = 0; s < 4; ++s){
      int seg = wave*4 + s;
      int rc = seg*8 + (lane >> 3);
      int ck = lane & 7;
      gload16(S + (r0 + rc)*1024 + kt + ck*8, (char*)As + seg*1024);
      gload16(Ct + ((long)n0 + rc)*1024 + kt + ck*8, (char*)Bs + seg*1024);
    }
    __syncthreads();
    #pragma unroll
    for (int kk = 0; kk < 2; ++kk){
      bf16x8 aF[4], bF[4];
      #pragma unroll
      for (int m = 0; m < 4; ++m)
        aF[m] = *(const bf16x8*)(As + (wr*64 + m*16 + (lane & 15))*64 + kk*32 + ((lane >> 4) << 3));
      #pragma unroll
      for (int n = 0; n < 4; ++n)
        bF[n] = *(const bf16x8*)(Bs + (wc*64 + n*16 + (lane & 15))*64 + kk*32 + ((lane >> 4) << 3));
      #pragma unroll
      for (int m = 0; m < 4; ++m)
        #pragma unroll
        for (int n = 0; n < 4; ++n)
          acc[m][n] = mfma16(aF[m], bF[n], acc[m][n]);
    }
    __syncthreads();
  }
  #pragma unroll
  for (int m = 0; m < 4; ++m)
    #pragma unroll
    for (int n = 0; n < 4; ++n)
      #pragma unroll
      for (int i = 0; i < 4; ++i){
        long row = r0 + wr*64 + m*16 + ((lane >> 4) << 2) + i;
        int col = n0 + wc*64 + n*16 + (lane & 15);
        Y[row*1024 + col] = acc[m][n][i];
      }
}

// ---------- overlap-add + on-the-fly direct term ----------
__global__ __launch_bounds__(256) void overlap_kernel(
    const float* __restrict__ Y, const float* __restrict__ ctrl,
    const float* __restrict__ PD, float* __restrict__ out)
{
  __shared__ float cl[9][32];
  int b = blockIdx.y, f0 = blockIdx.x * 8;
  int t = threadIdx.x;
  // 288 entries, 256 threads: strided loop (round-1 bug: `if (t<288)` left
  // channels 28..31 uninitialized -> absmax 2.4e-2)
  for (int idx = t; idx < 288; idx += 256){
    int c = idx / 9, fi = idx % 9;
    int f = f0 - 1 + fi;
    cl[fi][c] = (f >= 0) ? ctrl[((long)b*32 + c)*F_ + f] : 0.f;
  }
  __syncthreads();
  int lf = t >> 5, kb = (t & 31) * 16;
  int f = f0 + lf;
  float acc[16];
  {
    const float4* y1 = (const float4*)(Y + ((long)b*F_ + f)*1024 + kb);
    #pragma unroll
    for (int q = 0; q < 4; ++q){
      float4 v = y1[q];
      acc[q*4+0]=v.x; acc[q*4+1]=v.y; acc[q*4+2]=v.z; acc[q*4+3]=v.w;
    }
  }
  if (f > 0){
    const float4* y2 = (const float4*)(Y + ((long)b*F_ + f - 1)*1024 + 512 + kb);
    #pragma unroll
    for (int q = 0; q < 4; ++q){
      float4 v = y2[q];
      acc[q*4+0]+=v.x; acc[q*4+1]+=v.y; acc[q*4+2]+=v.z; acc[q*4+3]+=v.w;
    }
  }
  for (int c = 0; c < 32; ++c){
    float s1 = cl[lf+1][c];   // frame f
    float s0 = cl[lf][c];     // frame f-1 (0 when f==0)
    const float4* p1 = (const float4*)(PD + c*1024 + kb);
    const float4* p2 = (const float4*)(PD + c*1024 + 512 + kb);
    #pragma unroll
    for (int q = 0; q < 4; ++q){
      float4 a = p1[q], d = p2[q];
      acc[q*4+0] += s1*a.x + s0*d.x;
      acc[q*4+1] += s1*a.y + s0*d.y;
      acc[q*4+2] += s1*a.z + s0*d.z;
      acc[q*4+3] += s1*a.w + s0*d.w;
    }
  }
  float4* o = (float4*)(out + (long)b*(F_*HOP_) + (long)f*HOP_ + kb);
  #pragma unroll
  for (int q = 0; q < 4; ++q) o[q] = make_float4(acc[q*4+0], acc[q*4+1], acc[q*4+2], acc[q*4+3]);
}

extern "C" void kernel_launch(void* const* d_in, const int* in_sizes, int n_in,
                              void* d_out, int out_size, void* d_ws, size_t ws_size,
                              hipStream_t stream)
{
  const float* ctrl  = (const float*)d_in[0];  // [16][32][2048]
  const float* proj  = (const float*)d_in[1];  // [32][1024]
  const float* Ast   = (const float*)d_in[2];  // state_matrix [1024][1024]
  const float* Bin   = (const float*)d_in[3];  // input_matrix
  const float* Cout  = (const float*)d_in[4];  // output_matrix
  const float* Ddir  = (const float*)d_in[5];  // direct_matrix
  float* out = (float*)d_out;

  char* ws = (char*)d_ws;
  float* U   = (float*)(ws + 0);            // 134217728 B  [16][2048][1024] f32 (becomes Y)
  u16*  S    = (u16*)(ws + 134217728);      //  67108864 B  [16][2048][1024] bf16 states
  u16*  w0   = (u16*)(ws + 201326592);      //   2097152 B  warm ping [16][64][1024] bf16
  u16*  w1   = (u16*)(ws + 203423744);      //   2097152 B  warm pong
  u16*  AbT  = (u16*)(ws + 205520896);      //   2097152 B  state_matrix^T bf16
  u16*  CbT  = (u16*)(ws + 207618048);      //   2097152 B  output_matrix^T bf16
  float* PB  = (float*)(ws + 209715200);    //    131072 B  proj@input_matrix
  float* PD  = (float*)(ws + 209846272);    //    131072 B  proj@direct_matrix
  // total 209977344 B

  pb_kernel<<<dim3(8,32,2),128,0,stream>>>(proj, Bin, Ddir, PB, PD);
  tcast_kernel<<<dim3(16,16,2),256,0,stream>>>(Ast, Cout, AbT, CbT);
  uprep_kernel<<<dim3(256,16),256,0,stream>>>(ctrl, PB, U);

  for (int j = 0; j < STEPS_; ++j){
    const u16* src; int srcMode = 0, srcF0 = 0;
    u16* dst; int dstMode;
    int uF0 = j - W_;
    int hasPrev = (j > 0) ? 1 : 0;
    if (j == 0){ src = w0; }
    else if (j - 1 < W_){ src = ((j-1) & 1) ? w1 : w0; }
    else { src = S; srcMode = 1; srcF0 = j - 1 - W_; }
    if (j < W_){ dst = (j & 1) ? w1 : w0; dstMode = 0; }
    else { dst = S; dstMode = 1; }
    scan_step_kernel<<<dim3(16,16),256,0,stream>>>(src, srcMode, srcF0,
                                                   dst, dstMode, U, uF0, AbT, hasPrev);
  }

  ygemm_kernel<<<dim3(8,256),256,0,stream>>>(S, CbT, U);
  overlap_kernel<<<dim3(256,16),256,0,stream>>>(U, ctrl, PD, out);
}

// Round 3
// 542.830 us; speedup vs baseline: 3.0646x; 3.0646x over previous
//
#include <hip/hip_runtime.h>

typedef unsigned short u16;
typedef __bf16 bf16x8 __attribute__((ext_vector_type(8)));
typedef float f32x4 __attribute__((ext_vector_type(4)));
typedef u16 u16x8 __attribute__((ext_vector_type(8)));

#define B_ 16
#define F_ 2048
#define HOP_ 512
#define W_ 8
#define L_ 16
#define NSTEP_ 24   /* W_+L_ */
// S rows per batch: 2049 (guard row 0 = zeros, row f+1 = frame f)
// AuS rows per batch: 2056 (row f+8 = frame f; rows 0..7 zero for f<0)

typedef const __attribute__((address_space(1))) void* gas_t;
typedef __attribute__((address_space(3))) void* las_t;

__device__ __forceinline__ void gload16(const void* g, void* l){
  __builtin_amdgcn_global_load_lds((gas_t)g, (las_t)l, 16, 0, 0);
}

__device__ __forceinline__ u16 f2bf(float f){
  unsigned u = __float_as_uint(f);
  return (u16)((u + 0x7FFFu + ((u >> 16) & 1u)) >> 16);
}

__device__ __forceinline__ f32x4 mfma16(bf16x8 a, bf16x8 b, f32x4 c){
  return __builtin_amdgcn_mfma_f32_16x16x32_bf16(a, b, c, 0, 0, 0);
}

// ---------- PB = proj @ Min, PD = proj @ Mdir  (32x1024 each, f32) ----------
__global__ __launch_bounds__(128) void pb_kernel(
    const float* __restrict__ proj, const float* __restrict__ Min,
    const float* __restrict__ Mdir, float* __restrict__ PB, float* __restrict__ PD)
{
  int c = blockIdx.y;
  const float* M = blockIdx.z ? Mdir : Min;
  float* P = blockIdx.z ? PD : PB;
  int i = blockIdx.x * 128 + threadIdx.x;
  float a0=0.f,a1=0.f,a2=0.f,a3=0.f;
  for (int k = 0; k < 1024; k += 4){
    a0 += proj[c*1024+k+0] * M[(long)(k+0)*1024 + i];
    a1 += proj[c*1024+k+1] * M[(long)(k+1)*1024 + i];
    a2 += proj[c*1024+k+2] * M[(long)(k+2)*1024 + i];
    a3 += proj[c*1024+k+3] * M[(long)(k+3)*1024 + i];
  }
  P[c*1024 + i] = (a0+a1)+(a2+a3);
}

// ---------- transpose+cast: ABt[n][k]=Ast[k][n]; OBt[n][k]=C[k][n]; OBt[n][1024+k]=C[k][512+n]
__global__ __launch_bounds__(256) void tc2_kernel(
    const float* __restrict__ Ast, const float* __restrict__ Cout,
    u16* __restrict__ ABt, u16* __restrict__ OBt)
{
  int z = blockIdx.z;
  const float* src; u16* dst; long dstStride; int srcColOff, dstKOff, nLimit;
  if (z == 0){ src=Ast;  dst=ABt; dstStride=1088; srcColOff=0;   dstKOff=0;    nLimit=1024; }
  else if (z == 1){ src=Cout; dst=OBt; dstStride=2112; srcColOff=0;   dstKOff=0;    nLimit=512; }
  else { src=Cout; dst=OBt; dstStride=2112; srcColOff=512; dstKOff=1024; nLimit=512; }
  int n0 = blockIdx.x * 64;
  if (n0 >= nLimit) return;
  int k0 = blockIdx.y * 64;
  __shared__ float tile[64][65];
  int t = threadIdx.x;
  int r = t >> 2, cq = (t & 3) * 16;
  #pragma unroll
  for (int q = 0; q < 4; ++q){
    float4 v = *(const float4*)(src + (long)(k0 + r)*1024 + srcColOff + n0 + cq + q*4);
    tile[r][cq + q*4 + 0] = v.x; tile[r][cq + q*4 + 1] = v.y;
    tile[r][cq + q*4 + 2] = v.z; tile[r][cq + q*4 + 3] = v.w;
  }
  __syncthreads();
  u16x8 o0, o1;
  #pragma unroll
  for (int j = 0; j < 8; ++j) o0[j] = f2bf(tile[cq + j][r]);
  #pragma unroll
  for (int j = 0; j < 8; ++j) o1[j] = f2bf(tile[cq + 8 + j][r]);
  *(u16x8*)(dst + (long)(n0 + r)*dstStride + dstKOff + k0 + cq)     = o0;
  *(u16x8*)(dst + (long)(n0 + r)*dstStride + dstKOff + k0 + cq + 8) = o1;
}

// ---------- build Au rows from ctrl + zero guards ----------
__global__ __launch_bounds__(256) void aubuild_kernel(
    const float* __restrict__ ctrl, u16* __restrict__ AuS, u16* __restrict__ AuO,
    u16* __restrict__ S)
{
  __shared__ float ct[32][132];
  int b = blockIdx.y, f0 = blockIdx.x * 128;
  int t = threadIdx.x;
  for (int i = t; i < 32*129; i += 256){
    int cc = i / 129, fi = i % 129;
    int f = f0 - 1 + fi;
    ct[cc][fi] = (f >= 0) ? ctrl[((long)b*32 + cc)*F_ + f] : 0.f;
  }
  if (blockIdx.x == 0){
    AuS[(long)b*2056*64 + t] = 0;          // AuS rows 0..7 (frames -8..-1): 512 u16
    AuS[(long)b*2056*64 + 256 + t] = 0;
    *(uint2*)(S + (long)b*2049*1024 + t*4) = make_uint2(0u, 0u);  // S guard row
  }
  __syncthreads();
  int fo = t >> 1, half = t & 1;
  int f = f0 + fo;
  u16x8 v[4];
  #pragma unroll
  for (int g8 = 0; g8 < 4; ++g8)
    #pragma unroll
    for (int j = 0; j < 8; ++j)
      v[g8][j] = f2bf(half ? ct[g8*8+j][fo] : ct[g8*8+j][fo+1]);  // half1 = frame f-1
  u16* ao = AuO + ((long)b*2048 + f)*64 + half*32;
  #pragma unroll
  for (int g8 = 0; g8 < 4; ++g8) *(u16x8*)(ao + g8*8) = v[g8];
  u16* as_ = AuS + ((long)b*2056 + f + 8)*64 + half*32;
  if (half == 0){
    #pragma unroll
    for (int g8 = 0; g8 < 4; ++g8) *(u16x8*)(as_ + g8*8) = v[g8];
  } else {
    u16x8 z = {0,0,0,0,0,0,0,0};
    #pragma unroll
    for (int g8 = 0; g8 < 4; ++g8) *(u16x8*)(as_ + g8*8) = z;
  }
}

// ---------- fill aug K-columns of ABt (PB) and OBt (PD) ----------
__global__ __launch_bounds__(256) void augfill_kernel(
    const float* __restrict__ PB, const float* __restrict__ PD,
    u16* __restrict__ ABt, u16* __restrict__ OBt)
{
  int n = blockIdx.x * 256 + threadIdx.x;
  if (n < 1024){
    u16* p = ABt + (long)n*1088 + 1024;
    #pragma unroll 4
    for (int cc = 0; cc < 32; ++cc){
      p[cc] = f2bf(PB[cc*1024 + n]);
      p[32 + cc] = 0;
    }
  } else {
    int m = n - 1024;
    if (m >= 512) return;
    u16* p = OBt + (long)m*2112 + 2048;
    #pragma unroll 4
    for (int cc = 0; cc < 32; ++cc){
      p[cc] = f2bf(PD[cc*1024 + m]);
      p[32 + cc] = f2bf(PD[cc*1024 + 512 + m]);
    }
  }
}

// ---------- scan step: S_f = S_{f-1} @ A + ctrl_f @ PB  (aug-K GEMM, M=2048) ----------
__global__ __launch_bounds__(256) void scan2_kernel(
    const u16* __restrict__ src, int srcMode,
    u16* __restrict__ dst, int dstMode,
    const u16* __restrict__ AuS, const u16* __restrict__ ABt,
    int jmW, int hasPrev)
{
  __shared__ u16 As[64*64];
  __shared__ u16 Bs[64*64];
  int t = threadIdx.x, lane = t & 63, wave = t >> 6;
  int n0 = blockIdx.x * 64, r0 = blockIdx.y * 64;
  int wr = wave >> 1, wc = wave & 1;
  f32x4 acc[2][2];
  #pragma unroll
  for (int m = 0; m < 2; ++m)
    #pragma unroll
    for (int n = 0; n < 2; ++n) acc[m][n] = (f32x4){0.f,0.f,0.f,0.f};
  int ktBeg = hasPrev ? 0 : 16;
  for (int kt = ktBeg; kt <= 16; ++kt){
    #pragma unroll
    for (int s = 0; s < 2; ++s){
      int seg = wave*2 + s;
      int rc = seg*8 + (lane >> 3);
      int ck = lane & 7;
      int g = r0 + rc, b = g >> 7, ch = g & 127;
      int f = ch*L_ + jmW;
      const u16* ap; long aoff;
      if (kt < 16){
        ap = src;
        aoff = (srcMode ? ((long)b*2049 + f)*1024 : (long)g*1024) + kt*64;
      } else {
        ap = AuS;
        aoff = ((long)b*2056 + f + 8)*64;
      }
      gload16(ap + aoff + ck*8, (char*)As + seg*1024);
      gload16(ABt + (long)(n0 + rc)*1088 + kt*64 + ck*8, (char*)Bs + seg*1024);
    }
    __syncthreads();
    #pragma unroll
    for (int kk = 0; kk < 2; ++kk){
      bf16x8 aF[2], bF[2];
      #pragma unroll
      for (int m = 0; m < 2; ++m)
        aF[m] = *(const bf16x8*)(As + (wr*32 + m*16 + (lane & 15))*64 + kk*32 + ((lane >> 4) << 3));
      #pragma unroll
      for (int n = 0; n < 2; ++n)
        bF[n] = *(const bf16x8*)(Bs + (wc*32 + n*16 + (lane & 15))*64 + kk*32 + ((lane >> 4) << 3));
      #pragma unroll
      for (int m = 0; m < 2; ++m)
        #pragma unroll
        for (int n = 0; n < 2; ++n)
          acc[m][n] = mfma16(aF[m], bF[n], acc[m][n]);
    }
    __syncthreads();
  }
  #pragma unroll
  for (int m = 0; m < 2; ++m)
    #pragma unroll
    for (int n = 0; n < 2; ++n)
      #pragma unroll
      for (int i = 0; i < 4; ++i){
        int row = wr*32 + m*16 + ((lane >> 4) << 2) + i;
        int g = r0 + row, b = g >> 7, ch = g & 127;
        int f = ch*L_ + jmW;
        long doff = dstMode ? ((long)b*2049 + f + 1)*1024 : (long)g*1024;
        dst[doff + n0 + wc*32 + n*16 + (lane & 15)] = f2bf(acc[m][n][i]);
      }
}

// ---------- fused out = S@C(:, :512) + S[-1]@C(:, 512:) + direct (aug-K GEMM) ----------
__global__ __launch_bounds__(256) void outgemm_kernel(
    const u16* __restrict__ S, const u16* __restrict__ AuO,
    const u16* __restrict__ OBt, float* __restrict__ out)
{
  __shared__ u16 As[128*64];
  __shared__ u16 Bs[128*64];
  int id = blockIdx.x;
  int xcd = id & 7, q = id >> 3;
  int xt = q & 3;                 // n-tile (4)
  int yt = (q >> 2)*8 + xcd;      // m-tile (256), A-panel sharers co-XCD
  int n0 = xt * 128;
  long r0 = (long)yt * 128;
  int t = threadIdx.x, lane = t & 63, wave = t >> 6;
  int wr = wave >> 1, wc = wave & 1;
  f32x4 acc[4][4];
  #pragma unroll
  for (int m = 0; m < 4; ++m)
    #pragma unroll
    for (int n = 0; n < 4; ++n) acc[m][n] = (f32x4){0.f,0.f,0.f,0.f};
  for (int kt = 0; kt < 33; ++kt){
    #pragma unroll
    for (int s = 0; s < 4; ++s){
      int seg = wave*4 + s;
      int rc = seg*8 + (lane >> 3);
      int ck = lane & 7;
      long r = r0 + rc;
      int b = (int)(r >> 11), f = (int)(r & 2047);
      const u16* ap; long aoff;
      if (kt < 16){      ap = S;   aoff = ((long)b*2049 + f + 1)*1024 + kt*64; }
      else if (kt < 32){ ap = S;   aoff = ((long)b*2049 + f)*1024 + (kt-16)*64; }
      else {             ap = AuO; aoff = ((long)b*2048 + f)*64; }
      gload16(ap + aoff + ck*8, (char*)As + seg*1024);
      long koff = (kt < 16) ? (long)kt*64 : (kt < 32) ? 1024 + (long)(kt-16)*64 : 2048;
      gload16(OBt + (long)(n0 + rc)*2112 + koff + ck*8, (char*)Bs + seg*1024);
    }
    __syncthreads();
    #pragma unroll
    for (int kk = 0; kk < 2; ++kk){
      bf16x8 aF[4], bF[4];
      #pragma unroll
      for (int m = 0; m < 4; ++m)
        aF[m] = *(const bf16x8*)(As + (wr*64 + m*16 + (lane & 15))*64 + kk*32 + ((lane >> 4) << 3));
      #pragma unroll
      for (int n = 0; n < 4; ++n)
        bF[n] = *(const bf16x8*)(Bs + (wc*64 + n*16 + (lane & 15))*64 + kk*32 + ((lane >> 4) << 3));
      #pragma unroll
      for (int m = 0; m < 4; ++m)
        #pragma unroll
        for (int n = 0; n < 4; ++n)
          acc[m][n] = mfma16(aF[m], bF[n], acc[m][n]);
    }
    __syncthreads();
  }
  #pragma unroll
  for (int m = 0; m < 4; ++m)
    #pragma unroll
    for (int n = 0; n < 4; ++n)
      #pragma unroll
      for (int i = 0; i < 4; ++i){
        long r = r0 + wr*64 + m*16 + ((lane >> 4) << 2) + i;
        int b = (int)(r >> 11), f = (int)(r & 2047);
        out[(long)b*1048576 + (long)f*512 + n0 + wc*64 + n*16 + (lane & 15)] = acc[m][n][i];
      }
}

extern "C" void kernel_launch(void* const* d_in, const int* in_sizes, int n_in,
                              void* d_out, int out_size, void* d_ws, size_t ws_size,
                              hipStream_t stream)
{
  const float* ctrl = (const float*)d_in[0];  // [16][32][2048]
  const float* proj = (const float*)d_in[1];  // [32][1024]
  const float* Ast  = (const float*)d_in[2];  // state_matrix
  const float* Bin  = (const float*)d_in[3];  // input_matrix
  const float* Cout = (const float*)d_in[4];  // output_matrix
  const float* Ddir = (const float*)d_in[5];  // direct_matrix
  float* out = (float*)d_out;

  char* ws = (char*)d_ws;
  u16*  S   = (u16*)(ws + 0);           // 16*2049*1024*2 = 67,141,632 (row 0/batch = zero guard)
  u16*  w0  = (u16*)(ws + 67141632);    // 4,194,304 warmup ping [2048][1024]
  u16*  w1  = (u16*)(ws + 71335936);    // 4,194,304 warmup pong
  u16*  ABt = (u16*)(ws + 75530240);    // 1024*1088*2 = 2,228,224  [A;PB]^T bf16
  u16*  OBt = (u16*)(ws + 77758464);    // 512*2112*2 = 2,162,688   [C1;C2;PD1;PD2]^T bf16
  u16*  AuS = (u16*)(ws + 79921152);    // 16*2056*64*2 = 4,210,688 [ctrl_f|0]
  u16*  AuO = (u16*)(ws + 84131840);    // 16*2048*64*2 = 4,194,304 [ctrl_f|ctrl_{f-1}]
  float* PB = (float*)(ws + 88326144);  // 131,072
  float* PD = (float*)(ws + 88457216);  // 131,072  (end: 88,588,288)

  pb_kernel<<<dim3(8,32,2),128,0,stream>>>(proj, Bin, Ddir, PB, PD);
  tc2_kernel<<<dim3(16,16,3),256,0,stream>>>(Ast, Cout, ABt, OBt);
  aubuild_kernel<<<dim3(16,16),256,0,stream>>>(ctrl, AuS, AuO, S);
  augfill_kernel<<<6,256,0,stream>>>(PB, PD, ABt, OBt);

  for (int j = 0; j < NSTEP_; ++j){
    int hasPrev = (j > 0);
    int srcMode = (j >= 9);
    int dstMode = (j >= 8);
    const u16* src = srcMode ? (const u16*)S : (const u16*)((j & 1) ? w0 : w1); // w[(j-1)&1]
    u16* dst = dstMode ? S : ((j & 1) ? w1 : w0);                               // w[j&1]
    scan2_kernel<<<dim3(16,32),256,0,stream>>>(src, srcMode, dst, dstMode,
                                               AuS, ABt, j - W_, hasPrev);
  }

  outgemm_kernel<<<1024,256,0,stream>>>(S, AuO, OBt, out);
}

// Round 4
// 369.768 us; speedup vs baseline: 4.4989x; 1.4680x over previous
//
#include <hip/hip_runtime.h>

typedef unsigned short u16;
typedef __bf16 bf16x8 __attribute__((ext_vector_type(8)));
typedef float f32x4 __attribute__((ext_vector_type(4)));
typedef u16 u16x8 __attribute__((ext_vector_type(8)));
typedef u16 u16x4 __attribute__((ext_vector_type(4)));

#define F_ 2048

typedef const __attribute__((address_space(1))) void* gas_t;
typedef __attribute__((address_space(3))) void* las_t;

__device__ __forceinline__ void gload16(const void* g, void* l){
  __builtin_amdgcn_global_load_lds((gas_t)g, (las_t)l, 16, 0, 0);
}

__device__ __forceinline__ u16 f2bf(float f){
  unsigned u = __float_as_uint(f);
  return (u16)((u + 0x7FFFu + ((u >> 16) & 1u)) >> 16);
}

__device__ __forceinline__ f32x4 mfma16(bf16x8 a, bf16x8 b, f32x4 c){
  return __builtin_amdgcn_mfma_f32_16x16x32_bf16(a, b, c, 0, 0, 0);
}

// ---------- PB = proj @ Min (bf16 out, dup), PD = proj @ Mdir ----------
__global__ __launch_bounds__(128) void pb_kernel(
    const float* __restrict__ proj, const float* __restrict__ Min,
    const float* __restrict__ Mdir, u16* __restrict__ PBin,
    u16* __restrict__ PBmid, u16* __restrict__ PDb)
{
  int c = blockIdx.y;
  const float* M = blockIdx.z ? Mdir : Min;
  int i = blockIdx.x * 128 + threadIdx.x;
  float a0=0.f,a1=0.f,a2=0.f,a3=0.f;
  for (int k = 0; k < 1024; k += 4){
    a0 += proj[c*1024+k+0] * M[(long)(k+0)*1024 + i];
    a1 += proj[c*1024+k+1] * M[(long)(k+1)*1024 + i];
    a2 += proj[c*1024+k+2] * M[(long)(k+2)*1024 + i];
    a3 += proj[c*1024+k+3] * M[(long)(k+3)*1024 + i];
  }
  u16 v = f2bf((a0+a1)+(a2+a3));
  if (blockIdx.z == 0){ PBin[c*1024 + i] = v; PBmid[c*1024 + i] = v; }
  else PDb[c*1024 + i] = v;
}

// ---------- cast A -> bf16 row-major ----------
__global__ __launch_bounds__(256) void castA_kernel(
    const float* __restrict__ A, u16* __restrict__ Ab)
{
  long i = ((long)blockIdx.x*256 + threadIdx.x) * 4;
  float4 v = *(const float4*)(A + i);
  u16x4 o; o[0]=f2bf(v.x); o[1]=f2bf(v.y); o[2]=f2bf(v.z); o[3]=f2bf(v.w);
  *(u16x4*)(Ab + i) = o;
}

// ---------- transpose+cast: z0: At[n][k]=A[k][n]; z1/z2: OBt cols ----------
__global__ __launch_bounds__(256) void tc2_kernel(
    const float* __restrict__ Ast, const float* __restrict__ Cout,
    u16* __restrict__ At_, u16* __restrict__ OBt)
{
  int z = blockIdx.z;
  const float* src; u16* dst; long dstStride; int srcColOff, dstKOff, nLimit;
  if (z == 0){ src=Ast;  dst=At_; dstStride=1024; srcColOff=0;   dstKOff=0;    nLimit=1024; }
  else if (z == 1){ src=Cout; dst=OBt; dstStride=2112; srcColOff=0;   dstKOff=0;    nLimit=512; }
  else { src=Cout; dst=OBt; dstStride=2112; srcColOff=512; dstKOff=1024; nLimit=512; }
  int n0 = blockIdx.x * 64;
  if (n0 >= nLimit) return;
  int k0 = blockIdx.y * 64;
  __shared__ float tile[64][65];
  int t = threadIdx.x;
  int r = t >> 2, cq = (t & 3) * 16;
  #pragma unroll
  for (int q = 0; q < 4; ++q){
    float4 v = *(const float4*)(src + (long)(k0 + r)*1024 + srcColOff + n0 + cq + q*4);
    tile[r][cq + q*4 + 0] = v.x; tile[r][cq + q*4 + 1] = v.y;
    tile[r][cq + q*4 + 2] = v.z; tile[r][cq + q*4 + 3] = v.w;
  }
  __syncthreads();
  u16x8 o0, o1;
  #pragma unroll
  for (int j = 0; j < 8; ++j) o0[j] = f2bf(tile[cq + j][r]);
  #pragma unroll
  for (int j = 0; j < 8; ++j) o1[j] = f2bf(tile[cq + 8 + j][r]);
  *(u16x8*)(dst + (long)(n0 + r)*dstStride + dstKOff + k0 + cq)     = o0;
  *(u16x8*)(dst + (long)(n0 + r)*dstStride + dstKOff + k0 + cq + 8) = o1;
}

// ---------- ctrlT[b][f][cc] = bf16(ctrl[b][cc][f]) ----------
__global__ __launch_bounds__(256) void ctrlT_kernel(
    const float* __restrict__ ctrl, u16* __restrict__ ctrlT)
{
  __shared__ float tile[32][129];
  int b = blockIdx.y, f0 = blockIdx.x * 128, t = threadIdx.x;
  int cc = t >> 3, fq = (t & 7) * 16;
  #pragma unroll
  for (int q = 0; q < 4; ++q){
    float4 v = *(const float4*)(ctrl + ((long)b*32 + cc)*F_ + f0 + fq + q*4);
    tile[cc][fq+q*4+0]=v.x; tile[cc][fq+q*4+1]=v.y;
    tile[cc][fq+q*4+2]=v.z; tile[cc][fq+q*4+3]=v.w;
  }
  __syncthreads();
  int fl = t >> 1, h = t & 1;
  u16x8 lo, hi;
  #pragma unroll
  for (int j = 0; j < 8; ++j) lo[j] = f2bf(tile[h*16 + j][fl]);
  #pragma unroll
  for (int j = 0; j < 8; ++j) hi[j] = f2bf(tile[h*16 + 8 + j][fl]);
  long off = ((long)b*F_ + f0 + fl)*32 + h*16;
  *(u16x8*)(ctrlT + off) = lo;
  *(u16x8*)(ctrlT + off + 8) = hi;
}

// ---------- zero S guard rows + PBin rows 32..63 ----------
__global__ __launch_bounds__(256) void guard_kernel(u16* __restrict__ S, u16* __restrict__ PBin)
{
  int bid = blockIdx.x, t = threadIdx.x;
  u16x8 z = {0,0,0,0,0,0,0,0};
  if (bid < 16){
    if (t < 128) *(u16x8*)(S + (long)bid*2049*1024 + t*8) = z;
  } else {
    for (int q = 0; q < 16; ++q)
      *(u16x8*)(PBin + 32*1024 + (t*16 + q)*8) = z;
  }
}

// ---------- build AuS4 [b][f+16][128] and AuO [b][f][64] from ctrlT ----------
__global__ __launch_bounds__(256) void aubuild_kernel(
    const u16* __restrict__ ctrlT, u16* __restrict__ AuS4, u16* __restrict__ AuO)
{
  int b = blockIdx.y, t = threadIdx.x;
  if (blockIdx.z == 0){
    int ri = 8 + blockIdx.x*16 + (t >> 4);
    if (ri >= 2064) return;
    int chunk = t & 15, d = chunk >> 2, qq = chunk & 3;
    int f = ri - 16, fs = f - d;
    uint4 v = make_uint4(0u,0u,0u,0u);
    if (fs >= 0) v = *(const uint4*)(ctrlT + ((long)b*F_ + fs)*32 + qq*8);
    *(uint4*)(AuS4 + ((long)b*2064 + ri)*128 + chunk*8) = v;
  } else {
    if (blockIdx.x >= 64) return;
    int f = blockIdx.x*32 + (t >> 3);
    int chunk = t & 7, d = chunk >> 2, qq = chunk & 3;
    int fs = f - d;
    uint4 v = make_uint4(0u,0u,0u,0u);
    if (fs >= 0) v = *(const uint4*)(ctrlT + ((long)b*F_ + fs)*32 + qq*8);
    *(uint4*)(AuO + ((long)b*F_ + f)*64 + chunk*8) = v;
  }
}

// ---------- sq: C = A(rm) @ Bt ; optional row-major and transposed writes ----------
__global__ __launch_bounds__(256) void sq_kernel(
    const u16* __restrict__ A, const u16* __restrict__ Bt, long ldb,
    u16* __restrict__ Crm, u16* __restrict__ Ctr, long ldt)
{
  __shared__ u16 As[128*64];
  __shared__ u16 Bs[128*64];
  int t = threadIdx.x, lane = t & 63, wave = t >> 6;
  long r0 = (long)blockIdx.y * 128;
  int n0 = blockIdx.x * 128;
  int wr = wave >> 1, wc = wave & 1;
  f32x4 acc[4][4];
  #pragma unroll
  for (int m = 0; m < 4; ++m)
    #pragma unroll
    for (int n = 0; n < 4; ++n) acc[m][n] = (f32x4){0.f,0.f,0.f,0.f};
  for (int kt = 0; kt < 16; ++kt){
    #pragma unroll
    for (int s = 0; s < 4; ++s){
      int seg = wave*4 + s;
      int rc = seg*8 + (lane >> 3);
      int ck = lane & 7;
      gload16(A + (r0 + rc)*1024 + kt*64 + ck*8, (char*)As + seg*1024);
      gload16(Bt + ((long)n0 + rc)*ldb + kt*64 + ck*8, (char*)Bs + seg*1024);
    }
    __syncthreads();
    #pragma unroll
    for (int kk = 0; kk < 2; ++kk){
      bf16x8 aF[4], bF[4];
      #pragma unroll
      for (int m = 0; m < 4; ++m)
        aF[m] = *(const bf16x8*)(As + (wr*64 + m*16 + (lane & 15))*64 + kk*32 + ((lane >> 4) << 3));
      #pragma unroll
      for (int n = 0; n < 4; ++n)
        bF[n] = *(const bf16x8*)(Bs + (wc*64 + n*16 + (lane & 15))*64 + kk*32 + ((lane >> 4) << 3));
      #pragma unroll
      for (int m = 0; m < 4; ++m)
        #pragma unroll
        for (int n = 0; n < 4; ++n)
          acc[m][n] = mfma16(aF[m], bF[n], acc[m][n]);
    }
    __syncthreads();
  }
  #pragma unroll
  for (int m = 0; m < 4; ++m)
    #pragma unroll
    for (int n = 0; n < 4; ++n)
      #pragma unroll
      for (int i = 0; i < 4; ++i){
        long row = r0 + wr*64 + m*16 + ((lane >> 4) << 2) + i;
        int col = n0 + wc*64 + n*16 + (lane & 15);
        u16 v = f2bf(acc[m][n][i]);
        if (Crm) Crm[row*1024 + col] = v;
        if (Ctr) Ctr[(long)col*ldt + row] = v;
      }
}

// ---------- small 64-row GEMM: dst[writeOff+r] = src[r] @ Bt, r < nRows ----------
__global__ __launch_bounds__(256) void smallpb_kernel(
    const u16* __restrict__ src, const u16* __restrict__ Bt,
    u16* __restrict__ dst, int writeOff, int nRows)
{
  __shared__ u16 As[64*64];
  __shared__ u16 Bs[64*64];
  int t = threadIdx.x, lane = t & 63, wave = t >> 6;
  int n0 = blockIdx.x * 64;
  int wr = wave >> 1, wc = wave & 1;
  f32x4 acc[2][2];
  #pragma unroll
  for (int m = 0; m < 2; ++m)
    #pragma unroll
    for (int n = 0; n < 2; ++n) acc[m][n] = (f32x4){0.f,0.f,0.f,0.f};
  for (int kt = 0; kt < 16; ++kt){
    #pragma unroll
    for (int s = 0; s < 2; ++s){
      int seg = wave*2 + s;
      int rc = seg*8 + (lane >> 3);
      int ck = lane & 7;
      gload16(src + (long)rc*1024 + kt*64 + ck*8, (char*)As + seg*1024);
      gload16(Bt + ((long)n0 + rc)*1024 + kt*64 + ck*8, (char*)Bs + seg*1024);
    }
    __syncthreads();
    #pragma unroll
    for (int kk = 0; kk < 2; ++kk){
      bf16x8 aF[2], bF[2];
      #pragma unroll
      for (int m = 0; m < 2; ++m)
        aF[m] = *(const bf16x8*)(As + (wr*32 + m*16 + (lane & 15))*64 + kk*32 + ((lane >> 4) << 3));
      #pragma unroll
      for (int n = 0; n < 2; ++n)
        bF[n] = *(const bf16x8*)(Bs + (wc*32 + n*16 + (lane & 15))*64 + kk*32 + ((lane >> 4) << 3));
      #pragma unroll
      for (int m = 0; m < 2; ++m)
        #pragma unroll
        for (int n = 0; n < 2; ++n)
          acc[m][n] = mfma16(aF[m], bF[n], acc[m][n]);
    }
    __syncthreads();
  }
  #pragma unroll
  for (int m = 0; m < 2; ++m)
    #pragma unroll
    for (int n = 0; n < 2; ++n)
      #pragma unroll
      for (int i = 0; i < 4; ++i){
        int row = wr*32 + m*16 + ((lane >> 4) << 2) + i;
        if (row < nRows)
          dst[(long)(writeOff + row)*1024 + n0 + wc*32 + n*16 + (lane & 15)] = f2bf(acc[m][n][i]);
      }
}

// ---------- fill aug K-cols: SBt[n][1024+j]=PBd; OBt[m][2048+..]=PD ----------
__global__ __launch_bounds__(256) void augfill_kernel(
    const u16* __restrict__ PBin, const u16* __restrict__ PBmid,
    const u16* __restrict__ PBout, const u16* __restrict__ PDb,
    u16* __restrict__ SBt, u16* __restrict__ OBt)
{
  int n = blockIdx.x * 256 + threadIdx.x;
  if (n < 1024){
    u16* p = SBt + (long)n*1152 + 1024;
    for (int j = 0; j < 32; ++j)  p[j]      = PBin [(long)j*1024 + n];
    for (int j = 32; j < 64; ++j) p[j]      = PBmid[(long)j*1024 + n];
    for (int j = 0; j < 64; ++j)  p[64 + j] = PBout[(long)j*1024 + n];
  } else {
    int m = n - 1024;
    if (m >= 512) return;
    u16* p = OBt + (long)m*2112 + 2048;
    for (int cc = 0; cc < 32; ++cc){
      p[cc]      = PDb[cc*1024 + m];
      p[32 + cc] = PDb[cc*1024 + 512 + m];
    }
  }
}

// ---------- stride-4 scan step (swizzled 128^2 GEMM, M=8192, K=1152) ----------
// S_F = S_{F-4} @ A4 + [ctrl_F..ctrl_{F-3}] @ [PB0..PB3],  F = c*16 + p + fOff
__global__ __launch_bounds__(256) void scan4_kernel(
    const u16* __restrict__ sprev, int sprevMode,   // 0: [g][1024]; 1: S[b][F-4+1]
    u16* __restrict__ dout, int doutMode,           // 0: [g][1024]; 1: S[b][F+1]
    const u16* __restrict__ AuS4, const u16* __restrict__ SBt,
    int fOff, int ktBeg)
{
  __shared__ u16 As[128*64];
  __shared__ u16 Bs[128*64];
  int id = blockIdx.x;
  int xcd = id & 7, q = id >> 3;
  int xt = q & 7, yt = (q >> 3)*8 + xcd;
  int n0 = xt * 128, r0 = yt * 128;
  int b = r0 >> 9;
  int t = threadIdx.x, lane = t & 63, wave = t >> 6;
  int wr = wave >> 1, wc = wave & 1;
  f32x4 acc[4][4];
  #pragma unroll
  for (int m = 0; m < 4; ++m)
    #pragma unroll
    for (int n = 0; n < 4; ++n) acc[m][n] = (f32x4){0.f,0.f,0.f,0.f};
  for (int kt = ktBeg; kt < 18; ++kt){
    #pragma unroll
    for (int s = 0; s < 4; ++s){
      int seg = wave*4 + s;
      int rc = seg*8 + (lane >> 3);
      int ckg = (lane & 7) ^ ((lane >> 3) & 7);   // T2: inverse-swizzled source
      int g = r0 + rc;
      int c = (g & 511) >> 2, p = g & 3;
      int F = c*16 + p + fOff;
      const u16* ap; long aoff;
      if (kt < 16){
        ap = sprev;
        aoff = sprevMode ? ((long)b*2049 + F - 3)*1024 + kt*64
                         : (long)g*1024 + kt*64;
      } else {
        ap = AuS4;
        aoff = ((long)b*2064 + F + 16)*128 + (kt - 16)*64;
      }
      gload16(ap + aoff + ckg*8, (char*)As + seg*1024);
      gload16(SBt + (long)(n0 + rc)*1152 + kt*64 + ckg*8, (char*)Bs + seg*1024);
    }
    __syncthreads();
    #pragma unroll
    for (int kk = 0; kk < 2; ++kk){
      bf16x8 aF[4], bF[4];
      #pragma unroll
      for (int m = 0; m < 4; ++m){
        int ar = wr*64 + m*16 + (lane & 15);
        int ac = (kk*4 + (lane >> 4)) ^ (ar & 7);
        aF[m] = *(const bf16x8*)(As + ar*64 + (ac << 3));
      }
      #pragma unroll
      for (int n = 0; n < 4; ++n){
        int br = wc*64 + n*16 + (lane & 15);
        int bc = (kk*4 + (lane >> 4)) ^ (br & 7);
        bF[n] = *(const bf16x8*)(Bs + br*64 + (bc << 3));
      }
      #pragma unroll
      for (int m = 0; m < 4; ++m)
        #pragma unroll
        for (int n = 0; n < 4; ++n)
          acc[m][n] = mfma16(aF[m], bF[n], acc[m][n]);
    }
    __syncthreads();
  }
  #pragma unroll
  for (int m = 0; m < 4; ++m)
    #pragma unroll
    for (int n = 0; n < 4; ++n)
      #pragma unroll
      for (int i = 0; i < 4; ++i){
        int row = wr*64 + m*16 + ((lane >> 4) << 2) + i;
        int g = r0 + row;
        int c = (g & 511) >> 2, p = g & 3;
        int F = c*16 + p + fOff;
        int col = n0 + wc*64 + n*16 + (lane & 15);
        long doff = doutMode ? ((long)b*2049 + F + 1)*1024 : (long)g*1024;
        dout[doff + col] = f2bf(acc[m][n][i]);
      }
}

// ---------- fused out = S@C1 + S[-1]@C2 + direct (swizzled aug-K GEMM) ----------
__global__ __launch_bounds__(256) void outgemm_kernel(
    const u16* __restrict__ S, const u16* __restrict__ AuO,
    const u16* __restrict__ OBt, float* __restrict__ out)
{
  __shared__ u16 As[128*64];
  __shared__ u16 Bs[128*64];
  int id = blockIdx.x;
  int xcd = id & 7, q = id >> 3;
  int xt = q & 3;
  int yt = (q >> 2)*8 + xcd;
  int n0 = xt * 128;
  long r0 = (long)yt * 128;
  int t = threadIdx.x, lane = t & 63, wave = t >> 6;
  int wr = wave >> 1, wc = wave & 1;
  f32x4 acc[4][4];
  #pragma unroll
  for (int m = 0; m < 4; ++m)
    #pragma unroll
    for (int n = 0; n < 4; ++n) acc[m][n] = (f32x4){0.f,0.f,0.f,0.f};
  for (int kt = 0; kt < 33; ++kt){
    #pragma unroll
    for (int s = 0; s < 4; ++s){
      int seg = wave*4 + s;
      int rc = seg*8 + (lane >> 3);
      int ckg = (lane & 7) ^ ((lane >> 3) & 7);
      long r = r0 + rc;
      int b = (int)(r >> 11), f = (int)(r & 2047);
      const u16* ap; long aoff;
      if (kt < 16){      ap = S;   aoff = ((long)b*2049 + f + 1)*1024 + kt*64; }
      else if (kt < 32){ ap = S;   aoff = ((long)b*2049 + f)*1024 + (kt-16)*64; }
      else {             ap = AuO; aoff = ((long)b*F_ + f)*64; }
      gload16(ap + aoff + ckg*8, (char*)As + seg*1024);
      long koff = (kt < 16) ? (long)kt*64 : (kt < 32) ? 1024 + (long)(kt-16)*64 : 2048;
      gload16(OBt + (long)(n0 + rc)*2112 + koff + ckg*8, (char*)Bs + seg*1024);
    }
    __syncthreads();
    #pragma unroll
    for (int kk = 0; kk < 2; ++kk){
      bf16x8 aF[4], bF[4];
      #pragma unroll
      for (int m = 0; m < 4; ++m){
        int ar = wr*64 + m*16 + (lane & 15);
        int ac = (kk*4 + (lane >> 4)) ^ (ar & 7);
        aF[m] = *(const bf16x8*)(As + ar*64 + (ac << 3));
      }
      #pragma unroll
      for (int n = 0; n < 4; ++n){
        int br = wc*64 + n*16 + (lane & 15);
        int bc = (kk*4 + (lane >> 4)) ^ (br & 7);
        bF[n] = *(const bf16x8*)(Bs + br*64 + (bc << 3));
      }
      #pragma unroll
      for (int m = 0; m < 4; ++m)
        #pragma unroll
        for (int n = 0; n < 4; ++n)
          acc[m][n] = mfma16(aF[m], bF[n], acc[m][n]);
    }
    __syncthreads();
  }
  #pragma unroll
  for (int m = 0; m < 4; ++m)
    #pragma unroll
    for (int n = 0; n < 4; ++n)
      #pragma unroll
      for (int i = 0; i < 4; ++i){
        long r = r0 + wr*64 + m*16 + ((lane >> 4) << 2) + i;
        int b = (int)(r >> 11), f = (int)(r & 2047);
        out[(long)b*1048576 + (long)f*512 + n0 + wc*64 + n*16 + (lane & 15)] = acc[m][n][i];
      }
}

extern "C" void kernel_launch(void* const* d_in, const int* in_sizes, int n_in,
                              void* d_out, int out_size, void* d_ws, size_t ws_size,
                              hipStream_t stream)
{
  const float* ctrl = (const float*)d_in[0];  // [16][32][2048]
  const float* proj = (const float*)d_in[1];  // [32][1024]
  const float* Ast  = (const float*)d_in[2];  // state_matrix
  const float* Bin  = (const float*)d_in[3];  // input_matrix
  const float* Cout = (const float*)d_in[4];  // output_matrix
  const float* Ddir = (const float*)d_in[5];  // direct_matrix
  float* out = (float*)d_out;

  char* ws = (char*)d_ws;
  u16*  S     = (u16*)(ws + 0);             // 16*2049*1024*2 = 67,141,632 (row0/batch zero)
  u16*  Wa    = (u16*)(ws + 67141632);      // 8192*1024*2 = 16,777,216
  u16*  Wb    = (u16*)(ws + 83918848);      // 16,777,216
  u16*  SBt   = (u16*)(ws + 100696064);     // 1024*1152*2 = 2,359,296  [A4 | PB0..PB3]^T
  u16*  OBt   = (u16*)(ws + 103055360);     // 512*2112*2 = 2,162,688   [C1;C2;PD1;PD2]^T
  u16*  AuS4  = (u16*)(ws + 105218048);     // 16*2064*128*2 = 8,454,144
  u16*  AuO   = (u16*)(ws + 113672192);     // 16*2048*64*2 = 4,194,304
  u16*  ctrlT = (u16*)(ws + 117866496);     // 16*2048*32*2 = 2,097,152
  u16*  At_   = (u16*)(ws + 119963648);     // 2,097,152  A^T bf16
  u16*  Ab    = (u16*)(ws + 122060800);     // 2,097,152  A bf16 rm
  u16*  A2b   = (u16*)(ws + 124157952);     // 2,097,152  A^2 rm
  u16*  A2t   = (u16*)(ws + 126255104);     // 2,097,152  (A^2)^T
  u16*  PBin  = (u16*)(ws + 128352256);     // 64*1024*2 (rows 0-31 PB, 32-63 zero)
  u16*  PBmid = (u16*)(ws + 128483328);     // rows 0-31 PB, 32-63 PB@A
  u16*  PBout = (u16*)(ws + 128614400);     // rows 0-31 PB@A2, 32-63 PB@A3
  u16*  PDb   = (u16*)(ws + 128745472);     // 32*1024*2  (end 128,811,008)

  castA_kernel<<<1024,256,0,stream>>>(Ast, Ab);
  tc2_kernel<<<dim3(16,16,3),256,0,stream>>>(Ast, Cout, At_, OBt);
  pb_kernel<<<dim3(8,32,2),128,0,stream>>>(proj, Bin, Ddir, PBin, PBmid, PDb);
  ctrlT_kernel<<<dim3(16,16),256,0,stream>>>(ctrl, ctrlT);
  guard_kernel<<<17,256,0,stream>>>(S, PBin);
  aubuild_kernel<<<dim3(129,16,2),256,0,stream>>>(ctrlT, AuS4, AuO);

  // power/PB chain: A2 -> (PB@A, A4) -> (PB@A2, PB@A3)
  sq_kernel<<<dim3(8,8),256,0,stream>>>(Ab, At_, 1024, A2b, A2t, 1024);
  smallpb_kernel<<<16,256,0,stream>>>(PBin, At_, PBmid, 32, 32);       // PB1 -> PBmid[32:]
  sq_kernel<<<dim3(8,8),256,0,stream>>>(A2b, A2t, 1024, (u16*)0, SBt, 1152); // A4^T -> SBt
  smallpb_kernel<<<16,256,0,stream>>>(PBmid, A2t, PBout, 0, 64);       // PB2,PB3
  augfill_kernel<<<6,256,0,stream>>>(PBin, PBmid, PBout, PDb, SBt, OBt);

  // stride-4 scan: j=0,1 warmup (W=8 frames), j=2..5 real
  for (int j = 0; j < 6; ++j){
    int fOff = 4*(j - 2);
    const u16* sprev; int sprevMode;
    u16* dout; int doutMode;
    if (j == 0){ sprev = Wa; sprevMode = 0; }          // unused (ktBeg=16)
    else if (j == 1){ sprev = Wa; sprevMode = 0; }
    else if (j == 2){ sprev = Wb; sprevMode = 0; }
    else { sprev = S; sprevMode = 1; }
    if (j == 0){ dout = Wa; doutMode = 0; }
    else if (j == 1){ dout = Wb; doutMode = 0; }
    else { dout = S; doutMode = 1; }
    scan4_kernel<<<512,256,0,stream>>>(sprev, sprevMode, dout, doutMode,
                                       AuS4, SBt, fOff, (j == 0) ? 16 : 0);
  }

  outgemm_kernel<<<1024,256,0,stream>>>(S, AuO, OBt, out);
}

// Round 5
// 235.406 us; speedup vs baseline: 7.0667x; 1.5708x over previous
//
#include <hip/hip_runtime.h>

typedef unsigned short u16;
typedef __bf16 bf16x8 __attribute__((ext_vector_type(8)));
typedef float f32x4 __attribute__((ext_vector_type(4)));
typedef u16 u16x8 __attribute__((ext_vector_type(8)));
typedef u16 u16x4 __attribute__((ext_vector_type(4)));

#define F_ 2048

typedef const __attribute__((address_space(1))) void* gas_t;
typedef __attribute__((address_space(3))) void* las_t;

__device__ __forceinline__ void gload16(const void* g, void* l){
  __builtin_amdgcn_global_load_lds((gas_t)g, (las_t)l, 16, 0, 0);
}

__device__ __forceinline__ u16 f2bf(float f){
  unsigned u = __float_as_uint(f);
  return (u16)((u + 0x7FFFu + ((u >> 16) & 1u)) >> 16);
}

__device__ __forceinline__ f32x4 mfma16(bf16x8 a, bf16x8 b, f32x4 c){
  return __builtin_amdgcn_mfma_f32_16x16x32_bf16(a, b, c, 0, 0, 0);
}

// ---------- prepA: Ab (rm bf16) + At (transposed bf16) from f32 A ----------
__global__ __launch_bounds__(256) void prepA_kernel(
    const float* __restrict__ A, u16* __restrict__ Ab, u16* __restrict__ At)
{
  __shared__ float tile[64][65];
  int k0 = blockIdx.y * 64, i0 = blockIdx.x * 64;
  int t = threadIdx.x;
  int r = t >> 2, cq = (t & 3) * 16;
  #pragma unroll
  for (int q = 0; q < 4; ++q){
    float4 v = *(const float4*)(A + (long)(k0 + r)*1024 + i0 + cq + q*4);
    tile[r][cq + q*4 + 0] = v.x; tile[r][cq + q*4 + 1] = v.y;
    tile[r][cq + q*4 + 2] = v.z; tile[r][cq + q*4 + 3] = v.w;
    u16x4 o; o[0]=f2bf(v.x); o[1]=f2bf(v.y); o[2]=f2bf(v.z); o[3]=f2bf(v.w);
    *(u16x4*)(Ab + (long)(k0 + r)*1024 + i0 + cq + q*4) = o;
  }
  __syncthreads();
  u16x8 o0, o1;
  #pragma unroll
  for (int j = 0; j < 8; ++j) o0[j] = f2bf(tile[cq + j][r]);
  #pragma unroll
  for (int j = 0; j < 8; ++j) o1[j] = f2bf(tile[cq + 8 + j][r]);
  *(u16x8*)(At + (long)(i0 + r)*1024 + k0 + cq)     = o0;
  *(u16x8*)(At + (long)(i0 + r)*1024 + k0 + cq + 8) = o1;
}

// ---------- tcC: Ct2[n][k]=C[k][n] (z0), Ct2[n][1024+k]=C[k][512+n] (z1) ----------
__global__ __launch_bounds__(256) void tcC_kernel(
    const float* __restrict__ Cout, u16* __restrict__ Ct2)
{
  int z = blockIdx.z;
  int srcColOff = z ? 512 : 0, dstKOff = z ? 1024 : 0;
  int n0 = blockIdx.x * 64, k0 = blockIdx.y * 64;
  __shared__ float tile[64][65];
  int t = threadIdx.x;
  int r = t >> 2, cq = (t & 3) * 16;
  #pragma unroll
  for (int q = 0; q < 4; ++q){
    float4 v = *(const float4*)(Cout + (long)(k0 + r)*1024 + srcColOff + n0 + cq + q*4);
    tile[r][cq + q*4 + 0] = v.x; tile[r][cq + q*4 + 1] = v.y;
    tile[r][cq + q*4 + 2] = v.z; tile[r][cq + q*4 + 3] = v.w;
  }
  __syncthreads();
  u16x8 o0, o1;
  #pragma unroll
  for (int j = 0; j < 8; ++j) o0[j] = f2bf(tile[cq + j][r]);
  #pragma unroll
  for (int j = 0; j < 8; ++j) o1[j] = f2bf(tile[cq + 8 + j][r]);
  *(u16x8*)(Ct2 + (long)(n0 + r)*2048 + dstKOff + k0 + cq)     = o0;
  *(u16x8*)(Ct2 + (long)(n0 + r)*2048 + dstKOff + k0 + cq + 8) = o1;
}

// ---------- pb: Hs[0..31] = bf16(proj@Bin); PDf = f32(proj@Ddir) ----------
__global__ __launch_bounds__(128) void pb_kernel(
    const float* __restrict__ proj, const float* __restrict__ Min,
    const float* __restrict__ Mdir, u16* __restrict__ Hs, float* __restrict__ PDf)
{
  int c = blockIdx.y;
  const float* M = blockIdx.z ? Mdir : Min;
  int i = blockIdx.x * 128 + threadIdx.x;
  float a0=0.f,a1=0.f,a2=0.f,a3=0.f;
  for (int k = 0; k < 1024; k += 4){
    a0 += proj[c*1024+k+0] * M[(long)(k+0)*1024 + i];
    a1 += proj[c*1024+k+1] * M[(long)(k+1)*1024 + i];
    a2 += proj[c*1024+k+2] * M[(long)(k+2)*1024 + i];
    a3 += proj[c*1024+k+3] * M[(long)(k+3)*1024 + i];
  }
  float v = (a0+a1)+(a2+a3);
  if (blockIdx.z == 0) Hs[(long)c*1024 + i] = f2bf(v);
  else PDf[(long)c*1024 + i] = v;
}

// ---------- guardH: zero Hs rows 32..575 ----------
__global__ __launch_bounds__(256) void guardH_kernel(u16* __restrict__ Hs)
{
  long idx = ((long)blockIdx.x*256 + threadIdx.x)*8;
  u16x8 z = {0,0,0,0,0,0,0,0};
  *(u16x8*)(Hs + 32*1024 + idx) = z;
}

// ---------- lag: Lag[b][f][e*32+c] = bf16(ctrl[b][c][f-e]), e<=16, pad->0 ----------
__global__ __launch_bounds__(256) void lag_kernel(
    const float* __restrict__ ctrl, u16* __restrict__ Lag)
{
  __shared__ u16 LT[144][40];   // padded: bank-spread
  int b = blockIdx.y, f0 = blockIdx.x * 128, t = threadIdx.x;
  int c = t >> 3, fs = (t & 7) * 18;
  for (int q = 0; q < 18; ++q){
    int fi = fs + q;                 // 0..143
    int f = f0 - 16 + fi;
    float v = (f >= 0) ? ctrl[((long)b*32 + c)*F_ + f] : 0.f;
    LT[fi][c] = f2bf(v);
  }
  __syncthreads();
  u16x8 z = {0,0,0,0,0,0,0,0};
  for (int w = t; w < 128*72; w += 256){
    int row = w / 72, j = w % 72;
    int e = j >> 2, c0 = (j & 3) * 8;
    u16x8 v = z;
    if (e <= 16){
      #pragma unroll
      for (int q = 0; q < 8; ++q) v[q] = LT[row + 16 - e][c0 + q];
    }
    *(u16x8*)(Lag + ((long)b*F_ + f0 + row)*576 + j*8) = v;
  }
}

// ---------- sq: C = A(rm) @ Bt; writes rm (Crm) and/or transposed (Ctr) ----------
__global__ __launch_bounds__(256) void sq_kernel(
    const u16* __restrict__ A, const u16* __restrict__ Bt,
    u16* __restrict__ Crm, u16* __restrict__ Ctr)
{
  __shared__ u16 As[128*64];
  __shared__ u16 Bs[128*64];
  int t = threadIdx.x, lane = t & 63, wave = t >> 6;
  long r0 = (long)blockIdx.y * 128;
  int n0 = blockIdx.x * 128;
  int wr = wave >> 1, wc = wave & 1;
  f32x4 acc[4][4];
  #pragma unroll
  for (int m = 0; m < 4; ++m)
    #pragma unroll
    for (int n = 0; n < 4; ++n) acc[m][n] = (f32x4){0.f,0.f,0.f,0.f};
  for (int kt = 0; kt < 16; ++kt){
    #pragma unroll
    for (int s = 0; s < 4; ++s){
      int seg = wave*4 + s;
      int rc = seg*8 + (lane >> 3);
      int ckg = (lane & 7) ^ ((lane >> 3) & 7);
      gload16(A + (r0 + rc)*1024 + kt*64 + ckg*8, (char*)As + seg*1024);
      gload16(Bt + ((long)n0 + rc)*1024 + kt*64 + ckg*8, (char*)Bs + seg*1024);
    }
    __syncthreads();
    #pragma unroll
    for (int kk = 0; kk < 2; ++kk){
      bf16x8 aF[4], bF[4];
      #pragma unroll
      for (int m = 0; m < 4; ++m){
        int ar = wr*64 + m*16 + (lane & 15);
        int ac = (kk*4 + (lane >> 4)) ^ (ar & 7);
        aF[m] = *(const bf16x8*)(As + ar*64 + (ac << 3));
      }
      #pragma unroll
      for (int n = 0; n < 4; ++n){
        int br = wc*64 + n*16 + (lane & 15);
        int bc = (kk*4 + (lane >> 4)) ^ (br & 7);
        bF[n] = *(const bf16x8*)(Bs + br*64 + (bc << 3));
      }
      #pragma unroll
      for (int m = 0; m < 4; ++m)
        #pragma unroll
        for (int n = 0; n < 4; ++n)
          acc[m][n] = mfma16(aF[m], bF[n], acc[m][n]);
    }
    __syncthreads();
  }
  #pragma unroll
  for (int m = 0; m < 4; ++m)
    #pragma unroll
    for (int n = 0; n < 4; ++n)
      #pragma unroll
      for (int i = 0; i < 4; ++i){
        long row = r0 + wr*64 + m*16 + ((lane >> 4) << 2) + i;
        int col = n0 + wc*64 + n*16 + (lane & 15);
        u16 v = f2bf(acc[m][n][i]);
        if (Crm) Crm[row*1024 + col] = v;
        if (Ctr) Ctr[(long)col*1024 + row] = v;
      }
}

// ---------- smallh: Hs[outOff + rt*64 + r] = Hs[rt*64 + r] @ Bt (r<nRows mask) ----------
__global__ __launch_bounds__(256) void smallh_kernel(
    u16* __restrict__ Hs, const u16* __restrict__ Bt, int outOff, int nRows)
{
  __shared__ u16 As[64*64];
  __shared__ u16 Bs[64*64];
  int t = threadIdx.x, lane = t & 63, wave = t >> 6;
  int n0 = blockIdx.x * 64;
  int r0 = blockIdx.y * 64;
  int wr = wave >> 1, wc = wave & 1;
  f32x4 acc[2][2];
  #pragma unroll
  for (int m = 0; m < 2; ++m)
    #pragma unroll
    for (int n = 0; n < 2; ++n) acc[m][n] = (f32x4){0.f,0.f,0.f,0.f};
  for (int kt = 0; kt < 16; ++kt){
    #pragma unroll
    for (int s = 0; s < 2; ++s){
      int seg = wave*2 + s;
      int rc = seg*8 + (lane >> 3);
      int ckg = (lane & 7) ^ ((lane >> 3) & 7);
      gload16(Hs + (long)(r0 + rc)*1024 + kt*64 + ckg*8, (char*)As + seg*1024);
      gload16(Bt + ((long)n0 + rc)*1024 + kt*64 + ckg*8, (char*)Bs + seg*1024);
    }
    __syncthreads();
    #pragma unroll
    for (int kk = 0; kk < 2; ++kk){
      bf16x8 aF[2], bF[2];
      #pragma unroll
      for (int m = 0; m < 2; ++m){
        int ar = wr*32 + m*16 + (lane & 15);
        int ac = (kk*4 + (lane >> 4)) ^ (ar & 7);
        aF[m] = *(const bf16x8*)(As + ar*64 + (ac << 3));
      }
      #pragma unroll
      for (int n = 0; n < 2; ++n){
        int br = wc*32 + n*16 + (lane & 15);
        int bc = (kk*4 + (lane >> 4)) ^ (br & 7);
        bF[n] = *(const bf16x8*)(Bs + br*64 + (bc << 3));
      }
      #pragma unroll
      for (int m = 0; m < 2; ++m)
        #pragma unroll
        for (int n = 0; n < 2; ++n)
          acc[m][n] = mfma16(aF[m], bF[n], acc[m][n]);
    }
    __syncthreads();
  }
  #pragma unroll
  for (int m = 0; m < 2; ++m)
    #pragma unroll
    for (int n = 0; n < 2; ++n)
      #pragma unroll
      for (int i = 0; i < 4; ++i){
        int row = wr*32 + m*16 + ((lane >> 4) << 2) + i;
        if (row < nRows)
          Hs[(long)(outOff + r0 + row)*1024 + n0 + wc*32 + n*16 + (lane & 15)]
            = f2bf(acc[m][n][i]);
      }
}

// ---------- gbuild: Gt[n][m] = ([X1|X2] @ [C1;C2])[m][n] + PD terms ----------
// X1[m]=Hs[m] (rows>=512 are zero); X2[m]= m>=32 ? Hs[m-32] : Hs[544+m] (zeros)
__global__ __launch_bounds__(256) void gbuild_kernel(
    const u16* __restrict__ Hs, const u16* __restrict__ Ct2,
    const float* __restrict__ PDf, u16* __restrict__ Gt)
{
  __shared__ u16 As[64*64];
  __shared__ u16 Bs[64*64];
  int t = threadIdx.x, lane = t & 63, wave = t >> 6;
  int n0 = blockIdx.x * 64;
  int r0 = blockIdx.y * 64;
  int wr = wave >> 1, wc = wave & 1;
  f32x4 acc[2][2];
  #pragma unroll
  for (int m = 0; m < 2; ++m)
    #pragma unroll
    for (int n = 0; n < 2; ++n) acc[m][n] = (f32x4){0.f,0.f,0.f,0.f};
  for (int kt = 0; kt < 32; ++kt){
    #pragma unroll
    for (int s = 0; s < 2; ++s){
      int seg = wave*2 + s;
      int rc = seg*8 + (lane >> 3);
      int ckg = (lane & 7) ^ ((lane >> 3) & 7);
      int mg = r0 + rc;
      long aoff;
      if (kt < 16) aoff = (long)mg*1024 + kt*64;
      else {
        int row = (mg >= 32) ? (mg - 32) : (544 + mg);
        aoff = (long)row*1024 + (kt - 16)*64;
      }
      gload16(Hs + aoff + ckg*8, (char*)As + seg*1024);
      gload16(Ct2 + ((long)n0 + rc)*2048 + kt*64 + ckg*8, (char*)Bs + seg*1024);
    }
    __syncthreads();
    #pragma unroll
    for (int kk = 0; kk < 2; ++kk){
      bf16x8 aF[2], bF[2];
      #pragma unroll
      for (int m = 0; m < 2; ++m){
        int ar = wr*32 + m*16 + (lane & 15);
        int ac = (kk*4 + (lane >> 4)) ^ (ar & 7);
        aF[m] = *(const bf16x8*)(As + ar*64 + (ac << 3));
      }
      #pragma unroll
      for (int n = 0; n < 2; ++n){
        int br = wc*32 + n*16 + (lane & 15);
        int bc = (kk*4 + (lane >> 4)) ^ (br & 7);
        bF[n] = *(const bf16x8*)(Bs + br*64 + (bc << 3));
      }
      #pragma unroll
      for (int m = 0; m < 2; ++m)
        #pragma unroll
        for (int n = 0; n < 2; ++n)
          acc[m][n] = mfma16(aF[m], bF[n], acc[m][n]);
    }
    __syncthreads();
  }
  #pragma unroll
  for (int m = 0; m < 2; ++m)
    #pragma unroll
    for (int n = 0; n < 2; ++n)
      #pragma unroll
      for (int i = 0; i < 4; ++i){
        int mg = r0 + wr*32 + m*16 + ((lane >> 4) << 2) + i;
        int ng = n0 + wc*32 + n*16 + (lane & 15);
        float v = acc[m][n][i];
        if (mg < 32)       v += PDf[(long)mg*1024 + ng];
        else if (mg < 64)  v += PDf[(long)(mg-32)*1024 + 512 + ng];
        Gt[(long)ng*576 + mg] = f2bf(v);
      }
}

// ---------- main: out[r][n] = Lag[r][:] @ Gt[n][:]  (M=32768,K=576,N=512) ----------
__global__ __launch_bounds__(256) void main_kernel(
    const u16* __restrict__ Lag, const u16* __restrict__ Gt, float* __restrict__ out)
{
  __shared__ u16 As[128*64];
  __shared__ u16 Bs[128*64];
  int id = blockIdx.x;
  int xcd = id & 7, q = id >> 3;
  int xt = q & 3;
  int yt = (q >> 2)*8 + xcd;
  int n0 = xt * 128;
  long r0 = (long)yt * 128;
  int t = threadIdx.x, lane = t & 63, wave = t >> 6;
  int wr = wave >> 1, wc = wave & 1;
  f32x4 acc[4][4];
  #pragma unroll
  for (int m = 0; m < 4; ++m)
    #pragma unroll
    for (int n = 0; n < 4; ++n) acc[m][n] = (f32x4){0.f,0.f,0.f,0.f};
  for (int kt = 0; kt < 9; ++kt){
    #pragma unroll
    for (int s = 0; s < 4; ++s){
      int seg = wave*4 + s;
      int rc = seg*8 + (lane >> 3);
      int ckg = (lane & 7) ^ ((lane >> 3) & 7);
      gload16(Lag + (r0 + rc)*576 + kt*64 + ckg*8, (char*)As + seg*1024);
      gload16(Gt + ((long)n0 + rc)*576 + kt*64 + ckg*8, (char*)Bs + seg*1024);
    }
    __syncthreads();
    #pragma unroll
    for (int kk = 0; kk < 2; ++kk){
      bf16x8 aF[4], bF[4];
      #pragma unroll
      for (int m = 0; m < 4; ++m){
        int ar = wr*64 + m*16 + (lane & 15);
        int ac = (kk*4 + (lane >> 4)) ^ (ar & 7);
        aF[m] = *(const bf16x8*)(As + ar*64 + (ac << 3));
      }
      #pragma unroll
      for (int n = 0; n < 4; ++n){
        int br = wc*64 + n*16 + (lane & 15);
        int bc = (kk*4 + (lane >> 4)) ^ (br & 7);
        bF[n] = *(const bf16x8*)(Bs + br*64 + (bc << 3));
      }
      #pragma unroll
      for (int m = 0; m < 4; ++m)
        #pragma unroll
        for (int n = 0; n < 4; ++n)
          acc[m][n] = mfma16(aF[m], bF[n], acc[m][n]);
    }
    __syncthreads();
  }
  #pragma unroll
  for (int m = 0; m < 4; ++m)
    #pragma unroll
    for (int n = 0; n < 4; ++n)
      #pragma unroll
      for (int i = 0; i < 4; ++i){
        long r = r0 + wr*64 + m*16 + ((lane >> 4) << 2) + i;
        int col = n0 + wc*64 + n*16 + (lane & 15);
        out[r*512 + col] = acc[m][n][i];
      }
}

extern "C" void kernel_launch(void* const* d_in, const int* in_sizes, int n_in,
                              void* d_out, int out_size, void* d_ws, size_t ws_size,
                              hipStream_t stream)
{
  const float* ctrl = (const float*)d_in[0];  // [16][32][2048]
  const float* proj = (const float*)d_in[1];  // [32][1024]
  const float* Ast  = (const float*)d_in[2];  // state_matrix
  const float* Bin  = (const float*)d_in[3];  // input_matrix
  const float* Cout = (const float*)d_in[4];  // output_matrix
  const float* Ddir = (const float*)d_in[5];  // direct_matrix
  float* out = (float*)d_out;

  char* ws = (char*)d_ws;
  u16*  Lag = (u16*)(ws + 0);           // 32768*576*2 = 37,748,736
  u16*  Hs  = (u16*)(ws + 37748736);    // 576*1024*2 = 1,179,648 (rows 512..575 zero)
  u16*  Gt  = (u16*)(ws + 38928384);    // 512*576*2 = 589,824
  u16*  Ab  = (u16*)(ws + 39518208);    // 2,097,152
  u16*  At  = (u16*)(ws + 41615360);    // 2,097,152
  u16*  A2b = (u16*)(ws + 43712512);    // 2,097,152
  u16*  A2t = (u16*)(ws + 45809664);    // 2,097,152
  u16*  A4b = (u16*)(ws + 47906816);    // 2,097,152
  u16*  A4t = (u16*)(ws + 50003968);    // 2,097,152
  u16*  A8t = (u16*)(ws + 52101120);    // 2,097,152
  u16*  Ct2 = (u16*)(ws + 54198272);    // 512*2048*2 = 2,097,152
  float* PDf= (float*)(ws + 56295424);  // 131,072 (end 56,426,496)

  prepA_kernel<<<dim3(16,16),256,0,stream>>>(Ast, Ab, At);
  tcC_kernel<<<dim3(8,16,2),256,0,stream>>>(Cout, Ct2);
  pb_kernel<<<dim3(8,32,2),128,0,stream>>>(proj, Bin, Ddir, Hs, PDf);
  guardH_kernel<<<272,256,0,stream>>>(Hs);
  lag_kernel<<<dim3(16,16),256,0,stream>>>(ctrl, Lag);

  smallh_kernel<<<dim3(16,1),256,0,stream>>>(Hs, At, 32, 32);    // H1
  sq_kernel<<<dim3(8,8),256,0,stream>>>(Ab, At, A2b, A2t);       // A2
  smallh_kernel<<<dim3(16,1),256,0,stream>>>(Hs, A2t, 64, 64);   // H2,H3
  sq_kernel<<<dim3(8,8),256,0,stream>>>(A2b, A2t, A4b, A4t);     // A4
  smallh_kernel<<<dim3(16,2),256,0,stream>>>(Hs, A4t, 128, 128); // H4..7
  sq_kernel<<<dim3(8,8),256,0,stream>>>(A4b, A4t, (u16*)0, A8t); // A8^T
  smallh_kernel<<<dim3(16,4),256,0,stream>>>(Hs, A8t, 256, 256); // H8..15

  gbuild_kernel<<<dim3(8,9),256,0,stream>>>(Hs, Ct2, PDf, Gt);
  main_kernel<<<1024,256,0,stream>>>(Lag, Gt, out);
}

// Round 6
// 152.704 us; speedup vs baseline: 10.8939x; 1.5416x over previous
//
#include <hip/hip_runtime.h>

typedef unsigned short u16;
typedef __bf16 bf16x8 __attribute__((ext_vector_type(8)));
typedef float f32x4 __attribute__((ext_vector_type(4)));
typedef u16 u16x8 __attribute__((ext_vector_type(8)));
typedef u16 u16x4 __attribute__((ext_vector_type(4)));

#define F_ 2048

typedef const __attribute__((address_space(1))) void* gas_t;
typedef __attribute__((address_space(3))) void* las_t;

__device__ __forceinline__ void gload16(const void* g, void* l){
  __builtin_amdgcn_global_load_lds((gas_t)g, (las_t)l, 16, 0, 0);
}

__device__ __forceinline__ u16 f2bf(float f){
  unsigned u = __float_as_uint(f);
  return (u16)((u + 0x7FFFu + ((u >> 16) & 1u)) >> 16);
}

__device__ __forceinline__ f32x4 mfma16(bf16x8 a, bf16x8 b, f32x4 c){
  return __builtin_amdgcn_mfma_f32_16x16x32_bf16(a, b, c, 0, 0, 0);
}

// ---------- prepA: Ab (rm bf16) + At (transposed bf16) from f32 A ----------
__global__ __launch_bounds__(256) void prepA_kernel(
    const float* __restrict__ A, u16* __restrict__ Ab, u16* __restrict__ At)
{
  __shared__ float tile[64][65];
  int k0 = blockIdx.y * 64, i0 = blockIdx.x * 64;
  int t = threadIdx.x;
  int r = t >> 2, cq = (t & 3) * 16;
  #pragma unroll
  for (int q = 0; q < 4; ++q){
    float4 v = *(const float4*)(A + (long)(k0 + r)*1024 + i0 + cq + q*4);
    tile[r][cq + q*4 + 0] = v.x; tile[r][cq + q*4 + 1] = v.y;
    tile[r][cq + q*4 + 2] = v.z; tile[r][cq + q*4 + 3] = v.w;
    u16x4 o; o[0]=f2bf(v.x); o[1]=f2bf(v.y); o[2]=f2bf(v.z); o[3]=f2bf(v.w);
    *(u16x4*)(Ab + (long)(k0 + r)*1024 + i0 + cq + q*4) = o;
  }
  __syncthreads();
  u16x8 o0, o1;
  #pragma unroll
  for (int j = 0; j < 8; ++j) o0[j] = f2bf(tile[cq + j][r]);
  #pragma unroll
  for (int j = 0; j < 8; ++j) o1[j] = f2bf(tile[cq + 8 + j][r]);
  *(u16x8*)(At + (long)(i0 + r)*1024 + k0 + cq)     = o0;
  *(u16x8*)(At + (long)(i0 + r)*1024 + k0 + cq + 8) = o1;
}

// ---------- tcC: Ct2[n][k]=C[k][n] (z0), Ct2[n][1024+k]=C[k][512+n] (z1) ----------
__global__ __launch_bounds__(256) void tcC_kernel(
    const float* __restrict__ Cout, u16* __restrict__ Ct2)
{
  int z = blockIdx.z;
  int srcColOff = z ? 512 : 0, dstKOff = z ? 1024 : 0;
  int n0 = blockIdx.x * 64, k0 = blockIdx.y * 64;
  __shared__ float tile[64][65];
  int t = threadIdx.x;
  int r = t >> 2, cq = (t & 3) * 16;
  #pragma unroll
  for (int q = 0; q < 4; ++q){
    float4 v = *(const float4*)(Cout + (long)(k0 + r)*1024 + srcColOff + n0 + cq + q*4);
    tile[r][cq + q*4 + 0] = v.x; tile[r][cq + q*4 + 1] = v.y;
    tile[r][cq + q*4 + 2] = v.z; tile[r][cq + q*4 + 3] = v.w;
  }
  __syncthreads();
  u16x8 o0, o1;
  #pragma unroll
  for (int j = 0; j < 8; ++j) o0[j] = f2bf(tile[cq + j][r]);
  #pragma unroll
  for (int j = 0; j < 8; ++j) o1[j] = f2bf(tile[cq + 8 + j][r]);
  *(u16x8*)(Ct2 + (long)(n0 + r)*2048 + dstKOff + k0 + cq)     = o0;
  *(u16x8*)(Ct2 + (long)(n0 + r)*2048 + dstKOff + k0 + cq + 8) = o1;
}

// ---------- pbpart: split-K partials of proj@Min (z0) / proj@Mdir (z1) ----------
__global__ __launch_bounds__(128) void pbpart_kernel(
    const float* __restrict__ proj, const float* __restrict__ Min,
    const float* __restrict__ Mdir, float* __restrict__ PBp)
{
  int z = blockIdx.z, c = blockIdx.y;
  int iblk = blockIdx.x & 7, kc = blockIdx.x >> 3;
  const float* M = z ? Mdir : Min;
  int i = iblk * 128 + threadIdx.x;
  int k0 = kc * 128;
  float a0=0.f,a1=0.f,a2=0.f,a3=0.f;
  for (int k = 0; k < 128; k += 4){
    a0 += proj[c*1024 + k0+k+0] * M[(long)(k0+k+0)*1024 + i];
    a1 += proj[c*1024 + k0+k+1] * M[(long)(k0+k+1)*1024 + i];
    a2 += proj[c*1024 + k0+k+2] * M[(long)(k0+k+2)*1024 + i];
    a3 += proj[c*1024 + k0+k+3] * M[(long)(k0+k+3)*1024 + i];
  }
  PBp[(((long)z*8 + kc)*32 + c)*1024 + i] = (a0+a1)+(a2+a3);
}

// ---------- pbred: reduce partials -> Hs rows 0..31 (bf16) + PDf; zero Hs rows 512..575 ----------
__global__ __launch_bounds__(256) void pbred_kernel(
    const float* __restrict__ PBp, u16* __restrict__ Hs, float* __restrict__ PDf)
{
  int bx = blockIdx.x, t = threadIdx.x;
  if (bx < 256){
    int o = bx*256 + t;           // 0..65535
    int z = o >> 15, rem = o & 32767;
    float s = 0.f;
    #pragma unroll
    for (int kc = 0; kc < 8; ++kc)
      s += PBp[(((long)z*8 + kc) << 15) + rem];
    if (z == 0) Hs[rem] = f2bf(s);
    else        PDf[rem] = s;
  } else {
    long idx = ((long)(bx - 256)*256 + t)*8;   // 8192 vec8 = 64 rows
    u16x8 zv = {0,0,0,0,0,0,0,0};
    *(u16x8*)(Hs + 512*1024 + idx) = zv;
  }
}

// ---------- lag: Lag[b][f][e*32+c] = bf16(ctrl[b][c][f-e]), e=0..15 ----------
__global__ __launch_bounds__(256) void lag_kernel(
    const float* __restrict__ ctrl, u16* __restrict__ Lag)
{
  __shared__ u16 LT[144][40];
  int b = blockIdx.y, f0 = blockIdx.x * 128, t = threadIdx.x;
  int c = t >> 3, fs = (t & 7) * 18;
  for (int q = 0; q < 18; ++q){
    int fi = fs + q;                 // 0..143
    int f = f0 - 16 + fi;
    float v = (f >= 0) ? ctrl[((long)b*32 + c)*F_ + f] : 0.f;
    LT[fi][c] = f2bf(v);
  }
  __syncthreads();
  for (int w = t; w < 128*64; w += 256){
    int row = w >> 6, j = w & 63;
    int e = j >> 2, c0 = (j & 3) * 8;
    u16x8 v;
    #pragma unroll
    for (int q = 0; q < 8; ++q) v[q] = LT[row + 16 - e][c0 + q];
    *(u16x8*)(Lag + ((long)b*F_ + f0 + row)*512 + j*8) = v;
  }
}

// ---------- chain: one doubling stage.  rows<nA from Apow, else Hs[row-nA].
// out: rows<nA -> powRm/powTr; else Hs[hDst + (row-nA)] (masked to nH). BM=64,BN=128.
__global__ __launch_bounds__(256) void chain_kernel(
    const u16* __restrict__ Apow, const u16* __restrict__ HsSrc,
    const u16* __restrict__ Bt,
    u16* __restrict__ powRm, u16* __restrict__ powTr,
    u16* __restrict__ HsDst, int nA, int nH, int hDst)
{
  __shared__ u16 As[64*64];
  __shared__ u16 Bs[128*64];
  int t = threadIdx.x, lane = t & 63, wave = t >> 6;
  int n0 = blockIdx.x * 128, r0 = blockIdx.y * 64;
  int wr = wave >> 1, wc = wave & 1;
  f32x4 acc[2][4];
  #pragma unroll
  for (int m = 0; m < 2; ++m)
    #pragma unroll
    for (int n = 0; n < 4; ++n) acc[m][n] = (f32x4){0.f,0.f,0.f,0.f};
  for (int kt = 0; kt < 16; ++kt){
    int ckg = (lane & 7) ^ ((lane >> 3) & 7);
    #pragma unroll
    for (int s = 0; s < 4; ++s){
      int seg = wave*4 + s;
      int rc = seg*8 + (lane >> 3);
      gload16(Bt + (long)(n0 + rc)*1024 + kt*64 + ckg*8, (char*)Bs + seg*1024);
    }
    #pragma unroll
    for (int s = 0; s < 2; ++s){
      int seg = wave*2 + s;
      int rc = seg*8 + (lane >> 3);
      int row = r0 + rc;
      const u16* ap = (row < nA) ? (Apow + (long)row*1024)
                                 : (HsSrc + (long)(row - nA)*1024);
      gload16(ap + kt*64 + ckg*8, (char*)As + seg*1024);
    }
    __syncthreads();
    #pragma unroll
    for (int kk = 0; kk < 2; ++kk){
      bf16x8 aF[2], bF[4];
      #pragma unroll
      for (int m = 0; m < 2; ++m){
        int ar = wr*32 + m*16 + (lane & 15);
        int ac = (kk*4 + (lane >> 4)) ^ (ar & 7);
        aF[m] = *(const bf16x8*)(As + ar*64 + (ac << 3));
      }
      #pragma unroll
      for (int n = 0; n < 4; ++n){
        int br = wc*64 + n*16 + (lane & 15);
        int bc = (kk*4 + (lane >> 4)) ^ (br & 7);
        bF[n] = *(const bf16x8*)(Bs + br*64 + (bc << 3));
      }
      #pragma unroll
      for (int m = 0; m < 2; ++m)
        #pragma unroll
        for (int n = 0; n < 4; ++n)
          acc[m][n] = mfma16(aF[m], bF[n], acc[m][n]);
    }
    __syncthreads();
  }
  #pragma unroll
  for (int m = 0; m < 2; ++m)
    #pragma unroll
    for (int n = 0; n < 4; ++n)
      #pragma unroll
      for (int i = 0; i < 4; ++i){
        int row = r0 + wr*32 + m*16 + ((lane >> 4) << 2) + i;
        int col = n0 + wc*64 + n*16 + (lane & 15);
        u16 v = f2bf(acc[m][n][i]);
        if (row < nA){
          if (powRm) powRm[(long)row*1024 + col] = v;
          if (powTr) powTr[(long)col*1024 + row] = v;
        } else {
          int hr = row - nA;
          if (hr < nH) HsDst[(long)(hDst + hr)*1024 + col] = v;
        }
      }
}

// ---------- gbuild: Gt[n][m] = ([X1|X2] @ [C1;C2])[m][n] + PD terms ----------
__global__ __launch_bounds__(256) void gbuild_kernel(
    const u16* __restrict__ Hs, const u16* __restrict__ Ct2,
    const float* __restrict__ PDf, u16* __restrict__ Gt)
{
  __shared__ u16 As[64*64];
  __shared__ u16 Bs[64*64];
  int t = threadIdx.x, lane = t & 63, wave = t >> 6;
  int n0 = blockIdx.x * 64;
  int r0 = blockIdx.y * 64;
  int wr = wave >> 1, wc = wave & 1;
  f32x4 acc[2][2];
  #pragma unroll
  for (int m = 0; m < 2; ++m)
    #pragma unroll
    for (int n = 0; n < 2; ++n) acc[m][n] = (f32x4){0.f,0.f,0.f,0.f};
  for (int kt = 0; kt < 32; ++kt){
    #pragma unroll
    for (int s = 0; s < 2; ++s){
      int seg = wave*2 + s;
      int rc = seg*8 + (lane >> 3);
      int ckg = (lane & 7) ^ ((lane >> 3) & 7);
      int mg = r0 + rc;
      long aoff;
      if (kt < 16) aoff = (long)mg*1024 + kt*64;
      else {
        int row = (mg >= 32) ? (mg - 32) : (544 + mg);
        aoff = (long)row*1024 + (kt - 16)*64;
      }
      gload16(Hs + aoff + ckg*8, (char*)As + seg*1024);
      gload16(Ct2 + ((long)n0 + rc)*2048 + kt*64 + ckg*8, (char*)Bs + seg*1024);
    }
    __syncthreads();
    #pragma unroll
    for (int kk = 0; kk < 2; ++kk){
      bf16x8 aF[2], bF[2];
      #pragma unroll
      for (int m = 0; m < 2; ++m){
        int ar = wr*32 + m*16 + (lane & 15);
        int ac = (kk*4 + (lane >> 4)) ^ (ar & 7);
        aF[m] = *(const bf16x8*)(As + ar*64 + (ac << 3));
      }
      #pragma unroll
      for (int n = 0; n < 2; ++n){
        int br = wc*32 + n*16 + (lane & 15);
        int bc = (kk*4 + (lane >> 4)) ^ (br & 7);
        bF[n] = *(const bf16x8*)(Bs + br*64 + (bc << 3));
      }
      #pragma unroll
      for (int m = 0; m < 2; ++m)
        #pragma unroll
        for (int n = 0; n < 2; ++n)
          acc[m][n] = mfma16(aF[m], bF[n], acc[m][n]);
    }
    __syncthreads();
  }
  #pragma unroll
  for (int m = 0; m < 2; ++m)
    #pragma unroll
    for (int n = 0; n < 2; ++n)
      #pragma unroll
      for (int i = 0; i < 4; ++i){
        int mg = r0 + wr*32 + m*16 + ((lane >> 4) << 2) + i;
        int ng = n0 + wc*32 + n*16 + (lane & 15);
        float v = acc[m][n][i];
        if (mg < 32)       v += PDf[(long)mg*1024 + ng];
        else if (mg < 64)  v += PDf[(long)(mg-32)*1024 + 512 + ng];
        Gt[(long)ng*512 + mg] = f2bf(v);
      }
}

// ---------- main: out[r][n] = Lag[r][:] @ Gt[n][:]  (M=32768,K=512,N=512) ----------
__global__ __launch_bounds__(256) void main_kernel(
    const u16* __restrict__ Lag, const u16* __restrict__ Gt, float* __restrict__ out)
{
  __shared__ u16 As[128*64];
  __shared__ u16 Bs[128*64];
  int id = blockIdx.x;
  int xcd = id & 7, q = id >> 3;
  int xt = q & 3;
  int yt = (q >> 2)*8 + xcd;
  int n0 = xt * 128;
  long r0 = (long)yt * 128;
  int t = threadIdx.x, lane = t & 63, wave = t >> 6;
  int wr = wave >> 1, wc = wave & 1;
  f32x4 acc[4][4];
  #pragma unroll
  for (int m = 0; m < 4; ++m)
    #pragma unroll
    for (int n = 0; n < 4; ++n) acc[m][n] = (f32x4){0.f,0.f,0.f,0.f};
  for (int kt = 0; kt < 8; ++kt){
    #pragma unroll
    for (int s = 0; s < 4; ++s){
      int seg = wave*4 + s;
      int rc = seg*8 + (lane >> 3);
      int ckg = (lane & 7) ^ ((lane >> 3) & 7);
      gload16(Lag + (r0 + rc)*512 + kt*64 + ckg*8, (char*)As + seg*1024);
      gload16(Gt + ((long)n0 + rc)*512 + kt*64 + ckg*8, (char*)Bs + seg*1024);
    }
    __syncthreads();
    #pragma unroll
    for (int kk = 0; kk < 2; ++kk){
      bf16x8 aF[4], bF[4];
      #pragma unroll
      for (int m = 0; m < 4; ++m){
        int ar = wr*64 + m*16 + (lane & 15);
        int ac = (kk*4 + (lane >> 4)) ^ (ar & 7);
        aF[m] = *(const bf16x8*)(As + ar*64 + (ac << 3));
      }
      #pragma unroll
      for (int n = 0; n < 4; ++n){
        int br = wc*64 + n*16 + (lane & 15);
        int bc = (kk*4 + (lane >> 4)) ^ (br & 7);
        bF[n] = *(const bf16x8*)(Bs + br*64 + (bc << 3));
      }
      #pragma unroll
      for (int m = 0; m < 4; ++m)
        #pragma unroll
        for (int n = 0; n < 4; ++n)
          acc[m][n] = mfma16(aF[m], bF[n], acc[m][n]);
    }
    __syncthreads();
  }
  #pragma unroll
  for (int m = 0; m < 4; ++m)
    #pragma unroll
    for (int n = 0; n < 4; ++n)
      #pragma unroll
      for (int i = 0; i < 4; ++i){
        long r = r0 + wr*64 + m*16 + ((lane >> 4) << 2) + i;
        int col = n0 + wc*64 + n*16 + (lane & 15);
        out[r*512 + col] = acc[m][n][i];
      }
}

extern "C" void kernel_launch(void* const* d_in, const int* in_sizes, int n_in,
                              void* d_out, int out_size, void* d_ws, size_t ws_size,
                              hipStream_t stream)
{
  const float* ctrl = (const float*)d_in[0];  // [16][32][2048]
  const float* proj = (const float*)d_in[1];  // [32][1024]
  const float* Ast  = (const float*)d_in[2];  // state_matrix
  const float* Bin  = (const float*)d_in[3];  // input_matrix
  const float* Cout = (const float*)d_in[4];  // output_matrix
  const float* Ddir = (const float*)d_in[5];  // direct_matrix
  float* out = (float*)d_out;

  char* ws = (char*)d_ws;
  u16*  Lag = (u16*)(ws + 0);           // 32768*512*2 = 33,554,432
  u16*  Hs  = (u16*)(ws + 33554432);    // 576*1024*2 = 1,179,648 (rows 512..575 zero)
  u16*  Gt  = (u16*)(ws + 34734080);    // 512*512*2 = 524,288
  u16*  Ab  = (u16*)(ws + 35258368);    // 2,097,152
  u16*  At  = (u16*)(ws + 37355520);    // 2,097,152
  u16*  A2b = (u16*)(ws + 39452672);    // 2,097,152
  u16*  A2t = (u16*)(ws + 41549824);    // 2,097,152
  u16*  A4b = (u16*)(ws + 43646976);    // 2,097,152
  u16*  A4t = (u16*)(ws + 45744128);    // 2,097,152
  u16*  A8t = (u16*)(ws + 47841280);    // 2,097,152
  u16*  Ct2 = (u16*)(ws + 49938432);    // 512*2048*2 = 2,097,152
  float* PDf= (float*)(ws + 52035584);  // 131,072
  float* PBp= (float*)(ws + 52166656);  // 2*8*32*1024*4 = 2,097,152 (end 54,263,808)

  prepA_kernel<<<dim3(16,16),256,0,stream>>>(Ast, Ab, At);
  tcC_kernel<<<dim3(8,16,2),256,0,stream>>>(Cout, Ct2);
  pbpart_kernel<<<dim3(64,32,2),128,0,stream>>>(proj, Bin, Ddir, PBp);
  pbred_kernel<<<288,256,0,stream>>>(PBp, Hs, PDf);
  lag_kernel<<<dim3(16,16),256,0,stream>>>(ctrl, Lag);

  // doubling chain: 4 fused stages ([A-power ; H-block] @ A^k)
  chain_kernel<<<dim3(8,17),256,0,stream>>>(Ab,  Hs, At,  A2b, A2t, Hs, 1024,  32,  32); // A2,H1
  chain_kernel<<<dim3(8,17),256,0,stream>>>(A2b, Hs, A2t, A4b, A4t, Hs, 1024,  64,  64); // A4,H2-3
  chain_kernel<<<dim3(8,18),256,0,stream>>>(A4b, Hs, A4t, (u16*)0, A8t, Hs, 1024, 128, 128); // A8,H4-7
  chain_kernel<<<dim3(8,4), 256,0,stream>>>((u16*)0, Hs, A8t, (u16*)0, (u16*)0, Hs, 0, 256, 256); // H8-15

  gbuild_kernel<<<dim3(8,8),256,0,stream>>>(Hs, Ct2, PDf, Gt);
  main_kernel<<<1024,256,0,stream>>>(Lag, Gt, out);
}

// Round 7
// 142.433 us; speedup vs baseline: 11.6795x; 1.0721x over previous
//
#include <hip/hip_runtime.h>

typedef unsigned short u16;
typedef __bf16 bf16x8 __attribute__((ext_vector_type(8)));
typedef __bf16 bf16x4 __attribute__((ext_vector_type(4)));
typedef float f32x4 __attribute__((ext_vector_type(4)));
typedef u16 u16x8 __attribute__((ext_vector_type(8)));
typedef u16 u16x4 __attribute__((ext_vector_type(4)));

#define F_ 2048

typedef const __attribute__((address_space(1))) void* gas_t;
typedef __attribute__((address_space(3))) void* las_t;

__device__ __forceinline__ void gload16(const void* g, void* l){
  __builtin_amdgcn_global_load_lds((gas_t)g, (las_t)l, 16, 0, 0);
}

__device__ __forceinline__ u16 f2bf(float f){
  unsigned u = __float_as_uint(f);
  return (u16)((u + 0x7FFFu + ((u >> 16) & 1u)) >> 16);
}

__device__ __forceinline__ f32x4 mfma16(bf16x8 a, bf16x8 b, f32x4 c){
  return __builtin_amdgcn_mfma_f32_16x16x32_bf16(a, b, c, 0, 0, 0);
}

// ---------- prep1: fused prepA (id<256) / tcC (id<512) / pbpart (id<2560) ----------
__global__ __launch_bounds__(256) void prep1_kernel(
    const float* __restrict__ Ast, const float* __restrict__ Cout,
    const float* __restrict__ proj, const float* __restrict__ Min,
    const float* __restrict__ Mdir,
    u16* __restrict__ Ab, u16* __restrict__ At, u16* __restrict__ Ct2,
    float* __restrict__ PBp)
{
  __shared__ float tile[64][65];
  int id = blockIdx.x, t = threadIdx.x;
  if (id < 256){
    // prepA: Ab (rm bf16) + At (transposed bf16)
    int i0 = (id & 15) * 64, k0 = (id >> 4) * 64;
    int r = t >> 2, cq = (t & 3) * 16;
    #pragma unroll
    for (int q = 0; q < 4; ++q){
      float4 v = *(const float4*)(Ast + (long)(k0 + r)*1024 + i0 + cq + q*4);
      tile[r][cq + q*4 + 0] = v.x; tile[r][cq + q*4 + 1] = v.y;
      tile[r][cq + q*4 + 2] = v.z; tile[r][cq + q*4 + 3] = v.w;
      u16x4 o; o[0]=f2bf(v.x); o[1]=f2bf(v.y); o[2]=f2bf(v.z); o[3]=f2bf(v.w);
      *(u16x4*)(Ab + (long)(k0 + r)*1024 + i0 + cq + q*4) = o;
    }
    __syncthreads();
    u16x8 o0, o1;
    #pragma unroll
    for (int j = 0; j < 8; ++j) o0[j] = f2bf(tile[cq + j][r]);
    #pragma unroll
    for (int j = 0; j < 8; ++j) o1[j] = f2bf(tile[cq + 8 + j][r]);
    *(u16x8*)(At + (long)(i0 + r)*1024 + k0 + cq)     = o0;
    *(u16x8*)(At + (long)(i0 + r)*1024 + k0 + cq + 8) = o1;
  } else if (id < 512){
    // tcC: Ct2[n][k]=C[k][n] (z0), Ct2[n][1024+k]=C[k][512+n] (z1)
    int v = id - 256;
    int n0 = (v & 7) * 64, k0 = ((v >> 3) & 15) * 64, z = v >> 7;
    int srcColOff = z ? 512 : 0, dstKOff = z ? 1024 : 0;
    int r = t >> 2, cq = (t & 3) * 16;
    #pragma unroll
    for (int q = 0; q < 4; ++q){
      float4 v4 = *(const float4*)(Cout + (long)(k0 + r)*1024 + srcColOff + n0 + cq + q*4);
      tile[r][cq + q*4 + 0] = v4.x; tile[r][cq + q*4 + 1] = v4.y;
      tile[r][cq + q*4 + 2] = v4.z; tile[r][cq + q*4 + 3] = v4.w;
    }
    __syncthreads();
    u16x8 o0, o1;
    #pragma unroll
    for (int j = 0; j < 8; ++j) o0[j] = f2bf(tile[cq + j][r]);
    #pragma unroll
    for (int j = 0; j < 8; ++j) o1[j] = f2bf(tile[cq + 8 + j][r]);
    *(u16x8*)(Ct2 + (long)(n0 + r)*2048 + dstKOff + k0 + cq)     = o0;
    *(u16x8*)(Ct2 + (long)(n0 + r)*2048 + dstKOff + k0 + cq + 8) = o1;
  } else {
    // pbpart: split-K partials of proj@Min (z0) / proj@Mdir (z1)
    int v = id - 512;                 // 2048 blocks
    int z = v >> 10, rem = v & 1023;
    int c = rem >> 5, kc = (rem >> 2) & 7, iblk = rem & 3;
    const float* M = z ? Mdir : Min;
    int i = iblk * 256 + t;
    int k0 = kc * 128;
    float a0=0.f,a1=0.f,a2=0.f,a3=0.f;
    for (int k = 0; k < 128; k += 4){
      a0 += proj[c*1024 + k0+k+0] * M[(long)(k0+k+0)*1024 + i];
      a1 += proj[c*1024 + k0+k+1] * M[(long)(k0+k+1)*1024 + i];
      a2 += proj[c*1024 + k0+k+2] * M[(long)(k0+k+2)*1024 + i];
      a3 += proj[c*1024 + k0+k+3] * M[(long)(k0+k+3)*1024 + i];
    }
    PBp[(((long)z*8 + kc)*32 + c)*1024 + i] = (a0+a1)+(a2+a3);
  }
}

// ---------- pbred: reduce partials -> Hs rows 0..31 (bf16) + PDf; zero Hs rows 512..575 ----------
__global__ __launch_bounds__(256) void pbred_kernel(
    const float* __restrict__ PBp, u16* __restrict__ Hs, float* __restrict__ PDf)
{
  int bx = blockIdx.x, t = threadIdx.x;
  if (bx < 256){
    int o = bx*256 + t;           // 0..65535
    int z = o >> 15, rem = o & 32767;
    float s = 0.f;
    #pragma unroll
    for (int kc = 0; kc < 8; ++kc)
      s += PBp[(((long)z*8 + kc) << 15) + rem];
    if (z == 0) Hs[rem] = f2bf(s);
    else        PDf[rem] = s;
  } else {
    long idx = ((long)(bx - 256)*256 + t)*8;   // 8192 vec8 = 64 rows
    u16x8 zv = {0,0,0,0,0,0,0,0};
    *(u16x8*)(Hs + 512*1024 + idx) = zv;
  }
}

// ---------- chain: one doubling stage.  rows<nA from Apow, else Hs[row-nA]. ----------
__global__ __launch_bounds__(256) void chain_kernel(
    const u16* __restrict__ Apow, const u16* __restrict__ HsSrc,
    const u16* __restrict__ Bt,
    u16* __restrict__ powRm, u16* __restrict__ powTr,
    u16* __restrict__ HsDst, int nA, int nH, int hDst)
{
  __shared__ u16 As[64*64];
  __shared__ u16 Bs[128*64];
  int t = threadIdx.x, lane = t & 63, wave = t >> 6;
  int n0 = blockIdx.x * 128, r0 = blockIdx.y * 64;
  int wr = wave >> 1, wc = wave & 1;
  f32x4 acc[2][4];
  #pragma unroll
  for (int m = 0; m < 2; ++m)
    #pragma unroll
    for (int n = 0; n < 4; ++n) acc[m][n] = (f32x4){0.f,0.f,0.f,0.f};
  for (int kt = 0; kt < 16; ++kt){
    int ckg = (lane & 7) ^ ((lane >> 3) & 7);
    #pragma unroll
    for (int s = 0; s < 4; ++s){
      int seg = wave*4 + s;
      int rc = seg*8 + (lane >> 3);
      gload16(Bt + (long)(n0 + rc)*1024 + kt*64 + ckg*8, (char*)Bs + seg*1024);
    }
    #pragma unroll
    for (int s = 0; s < 2; ++s){
      int seg = wave*2 + s;
      int rc = seg*8 + (lane >> 3);
      int row = r0 + rc;
      const u16* ap = (row < nA) ? (Apow + (long)row*1024)
                                 : (HsSrc + (long)(row - nA)*1024);
      gload16(ap + kt*64 + ckg*8, (char*)As + seg*1024);
    }
    __syncthreads();
    #pragma unroll
    for (int kk = 0; kk < 2; ++kk){
      bf16x8 aF[2], bF[4];
      #pragma unroll
      for (int m = 0; m < 2; ++m){
        int ar = wr*32 + m*16 + (lane & 15);
        int ac = (kk*4 + (lane >> 4)) ^ (ar & 7);
        aF[m] = *(const bf16x8*)(As + ar*64 + (ac << 3));
      }
      #pragma unroll
      for (int n = 0; n < 4; ++n){
        int br = wc*64 + n*16 + (lane & 15);
        int bc = (kk*4 + (lane >> 4)) ^ (br & 7);
        bF[n] = *(const bf16x8*)(Bs + br*64 + (bc << 3));
      }
      #pragma unroll
      for (int m = 0; m < 2; ++m)
        #pragma unroll
        for (int n = 0; n < 4; ++n)
          acc[m][n] = mfma16(aF[m], bF[n], acc[m][n]);
    }
    __syncthreads();
  }
  #pragma unroll
  for (int m = 0; m < 2; ++m)
    #pragma unroll
    for (int n = 0; n < 4; ++n)
      #pragma unroll
      for (int i = 0; i < 4; ++i){
        int row = r0 + wr*32 + m*16 + ((lane >> 4) << 2) + i;
        int col = n0 + wc*64 + n*16 + (lane & 15);
        u16 v = f2bf(acc[m][n][i]);
        if (row < nA){
          if (powRm) powRm[(long)row*1024 + col] = v;
          if (powTr) powTr[(long)col*1024 + row] = v;
        } else {
          int hr = row - nA;
          if (hr < nH) HsDst[(long)(hDst + hr)*1024 + col] = v;
        }
      }
}

// ---------- gbuild: Gt[n][m] = ([X1|X2] @ [C1;C2])[m][n] + PD terms ----------
__global__ __launch_bounds__(256) void gbuild_kernel(
    const u16* __restrict__ Hs, const u16* __restrict__ Ct2,
    const float* __restrict__ PDf, u16* __restrict__ Gt)
{
  __shared__ u16 As[64*64];
  __shared__ u16 Bs[64*64];
  int t = threadIdx.x, lane = t & 63, wave = t >> 6;
  int n0 = blockIdx.x * 64;
  int r0 = blockIdx.y * 64;
  int wr = wave >> 1, wc = wave & 1;
  f32x4 acc[2][2];
  #pragma unroll
  for (int m = 0; m < 2; ++m)
    #pragma unroll
    for (int n = 0; n < 2; ++n) acc[m][n] = (f32x4){0.f,0.f,0.f,0.f};
  for (int kt = 0; kt < 32; ++kt){
    #pragma unroll
    for (int s = 0; s < 2; ++s){
      int seg = wave*2 + s;
      int rc = seg*8 + (lane >> 3);
      int ckg = (lane & 7) ^ ((lane >> 3) & 7);
      int mg = r0 + rc;
      long aoff;
      if (kt < 16) aoff = (long)mg*1024 + kt*64;
      else {
        int row = (mg >= 32) ? (mg - 32) : (544 + mg);
        aoff = (long)row*1024 + (kt - 16)*64;
      }
      gload16(Hs + aoff + ckg*8, (char*)As + seg*1024);
      gload16(Ct2 + ((long)n0 + rc)*2048 + kt*64 + ckg*8, (char*)Bs + seg*1024);
    }
    __syncthreads();
    #pragma unroll
    for (int kk = 0; kk < 2; ++kk){
      bf16x8 aF[2], bF[2];
      #pragma unroll
      for (int m = 0; m < 2; ++m){
        int ar = wr*32 + m*16 + (lane & 15);
        int ac = (kk*4 + (lane >> 4)) ^ (ar & 7);
        aF[m] = *(const bf16x8*)(As + ar*64 + (ac << 3));
      }
      #pragma unroll
      for (int n = 0; n < 2; ++n){
        int br = wc*32 + n*16 + (lane & 15);
        int bc = (kk*4 + (lane >> 4)) ^ (br & 7);
        bF[n] = *(const bf16x8*)(Bs + br*64 + (bc << 3));
      }
      #pragma unroll
      for (int m = 0; m < 2; ++m)
        #pragma unroll
        for (int n = 0; n < 2; ++n)
          acc[m][n] = mfma16(aF[m], bF[n], acc[m][n]);
    }
    __syncthreads();
  }
  #pragma unroll
  for (int m = 0; m < 2; ++m)
    #pragma unroll
    for (int n = 0; n < 2; ++n)
      #pragma unroll
      for (int i = 0; i < 4; ++i){
        int mg = r0 + wr*32 + m*16 + ((lane >> 4) << 2) + i;
        int ng = n0 + wc*32 + n*16 + (lane & 15);
        float v = acc[m][n][i];
        if (mg < 32)       v += PDf[(long)mg*1024 + ng];
        else if (mg < 64)  v += PDf[(long)(mg-32)*1024 + 512 + ng];
        Gt[(long)ng*512 + mg] = f2bf(v);
      }
}

// ---------- mainf: out[b][f][n] = sum_{e,c} ctrl[b][c][f-e] * Gt[n][e*32+c] ----------
// A-operand synthesized from LDS ctrl tile (lag fusion): M=32768, K=512, N=512
__global__ __launch_bounds__(256) void mainf_kernel(
    const float* __restrict__ ctrl, const u16* __restrict__ Gt, float* __restrict__ out)
{
  __shared__ u16 LT[144][36];     // frames f0-16 .. f0+127, 32 ch (+4 pad: 4-way max)
  __shared__ u16 Bs[128*64];
  int id = blockIdx.x;
  int xcd = id & 7, q = id >> 3;
  int xt = q & 3;
  int yt = (q >> 2)*8 + xcd;      // n-tiles of one row-panel co-XCD
  int n0 = xt * 128;
  long r0 = (long)yt * 128;
  int b = (int)(r0 >> 11), f0 = (int)(r0 & 2047);
  int t = threadIdx.x, lane = t & 63, wave = t >> 6;
  int wr = wave >> 1, wc = wave & 1;
  // stage ctrl tile -> LT[fi][c], fi = f - (f0-16)
  {
    int c = t >> 3, fs = (t & 7) * 18;
    for (int qq = 0; qq < 18; ++qq){
      int fi = fs + qq;                       // 0..143
      int f = f0 - 16 + fi;
      float v = (f >= 0) ? ctrl[((long)b*32 + c)*F_ + f] : 0.f;
      LT[fi][c] = f2bf(v);
    }
  }
  f32x4 acc[4][4];
  #pragma unroll
  for (int m = 0; m < 4; ++m)
    #pragma unroll
    for (int n = 0; n < 4; ++n) acc[m][n] = (f32x4){0.f,0.f,0.f,0.f};
  for (int kt = 0; kt < 8; ++kt){
    #pragma unroll
    for (int s = 0; s < 4; ++s){
      int seg = wave*4 + s;
      int rc = seg*8 + (lane >> 3);
      int ckg = (lane & 7) ^ ((lane >> 3) & 7);
      gload16(Gt + ((long)n0 + rc)*512 + kt*64 + ckg*8, (char*)Bs + seg*1024);
    }
    __syncthreads();                          // covers LT build (kt=0) + Bs
    int c0 = (lane >> 4) << 3;
    #pragma unroll
    for (int kk = 0; kk < 2; ++kk){
      int e = kt*2 + kk;                      // lag index of this 32-k chunk
      bf16x8 aF[4], bF[4];
      #pragma unroll
      for (int m = 0; m < 4; ++m){
        int ar = wr*64 + m*16 + (lane & 15);
        const u16* p = &LT[ar + 16 - e][c0];
        bf16x4 lo = *(const bf16x4*)p;
        bf16x4 hi = *(const bf16x4*)(p + 4);
        bf16x8 a;
        a[0]=lo[0]; a[1]=lo[1]; a[2]=lo[2]; a[3]=lo[3];
        a[4]=hi[0]; a[5]=hi[1]; a[6]=hi[2]; a[7]=hi[3];
        aF[m] = a;
      }
      #pragma unroll
      for (int n = 0; n < 4; ++n){
        int br = wc*64 + n*16 + (lane & 15);
        int bc = (kk*4 + (lane >> 4)) ^ (br & 7);
        bF[n] = *(const bf16x8*)(Bs + br*64 + (bc << 3));
      }
      #pragma unroll
      for (int m = 0; m < 4; ++m)
        #pragma unroll
        for (int n = 0; n < 4; ++n)
          acc[m][n] = mfma16(aF[m], bF[n], acc[m][n]);
    }
    __syncthreads();
  }
  #pragma unroll
  for (int m = 0; m < 4; ++m)
    #pragma unroll
    for (int n = 0; n < 4; ++n)
      #pragma unroll
      for (int i = 0; i < 4; ++i){
        long r = r0 + wr*64 + m*16 + ((lane >> 4) << 2) + i;
        int col = n0 + wc*64 + n*16 + (lane & 15);
        out[r*512 + col] = acc[m][n][i];
      }
}

extern "C" void kernel_launch(void* const* d_in, const int* in_sizes, int n_in,
                              void* d_out, int out_size, void* d_ws, size_t ws_size,
                              hipStream_t stream)
{
  const float* ctrl = (const float*)d_in[0];  // [16][32][2048]
  const float* proj = (const float*)d_in[1];  // [32][1024]
  const float* Ast  = (const float*)d_in[2];  // state_matrix
  const float* Bin  = (const float*)d_in[3];  // input_matrix
  const float* Cout = (const float*)d_in[4];  // output_matrix
  const float* Ddir = (const float*)d_in[5];  // direct_matrix
  float* out = (float*)d_out;

  char* ws = (char*)d_ws;
  u16*  Hs  = (u16*)(ws + 0);           // 576*1024*2 = 1,179,648 (rows 512..575 zero)
  u16*  Gt  = (u16*)(ws + 1179648);     // 512*512*2 = 524,288
  u16*  Ab  = (u16*)(ws + 1703936);     // 2,097,152
  u16*  At  = (u16*)(ws + 3801088);     // 2,097,152
  u16*  A2b = (u16*)(ws + 5898240);     // 2,097,152
  u16*  A2t = (u16*)(ws + 7995392);     // 2,097,152
  u16*  A4b = (u16*)(ws + 10092544);    // 2,097,152
  u16*  A4t = (u16*)(ws + 12189696);    // 2,097,152
  u16*  A8t = (u16*)(ws + 14286848);    // 2,097,152
  u16*  Ct2 = (u16*)(ws + 16384000);    // 512*2048*2 = 2,097,152
  float* PDf= (float*)(ws + 18481152);  // 131,072
  float* PBp= (float*)(ws + 18612224);  // 2,097,152 (end 20,709,376)

  prep1_kernel<<<2560,256,0,stream>>>(Ast, Cout, proj, Bin, Ddir, Ab, At, Ct2, PBp);
  pbred_kernel<<<288,256,0,stream>>>(PBp, Hs, PDf);

  // doubling chain: 4 fused stages ([A-power ; H-block] @ A^k)
  chain_kernel<<<dim3(8,17),256,0,stream>>>(Ab,  Hs, At,  A2b, A2t, Hs, 1024,  32,  32); // A2,H1
  chain_kernel<<<dim3(8,17),256,0,stream>>>(A2b, Hs, A2t, A4b, A4t, Hs, 1024,  64,  64); // A4,H2-3
  chain_kernel<<<dim3(8,18),256,0,stream>>>(A4b, Hs, A4t, (u16*)0, A8t, Hs, 1024, 128, 128); // A8,H4-7
  chain_kernel<<<dim3(8,4), 256,0,stream>>>((u16*)0, Hs, A8t, (u16*)0, (u16*)0, Hs, 0, 256, 256); // H8-15

  gbuild_kernel<<<dim3(8,8),256,0,stream>>>(Hs, Ct2, PDf, Gt);
  mainf_kernel<<<1024,256,0,stream>>>(ctrl, Gt, out);
}